// Round 1
// baseline (227.461 us; speedup 1.0000x reference)
//
#include <hip/hip_runtime.h>

#define A_ 16
#define NA_ 8
#define DOBS_ 64

typedef _Float16 f16;
typedef f16 h2 __attribute__((ext_vector_type(2)));

__device__ __forceinline__ float fdot2f(h2 a, h2 b, float c) {
  return __builtin_amdgcn_fdot2(a, b, c, false);
}
__device__ __forceinline__ h2 as_h2(float x) { return __builtin_bit_cast(h2, x); }
__device__ __forceinline__ float lrelu(float x) { return x > 0.f ? x : 0.01f * x; }

struct R1 { float a1[16][68]; float a2[16][68]; float a3[16][68]; float ht[16][68]; };
struct R2 { h2 AOs[32][256]; h2 APs[32][16]; };

struct alignas(16) SMem {
  float obs[16][68];      // padded rows (bank-conflict-free j-varying reads)
  float pi[16][8];
  float act[16][8];
  float wsig[16][16];     // sigmoid weights w
  float wo[16][16];       // softmaxed weights_o
  float c0[16];           // keyo . b2qo
  f16   htap[16][72];     // AP layer-1 hidden
  union { R1 r1; R2 r2; } u;             // 34816 B
  union { float f[4928]; f16 h[9856]; } wb; // rotating weight staging, 19712 B
};

struct P {
  const float *obs, *pol, *act;
  const float *kw1w, *kw1b, *kw2w, *kw2b, *qw1w, *qw1b, *qw2w, *qw2b;
  const float *ko1w, *ko1b, *ko2w, *ko2b, *qo1w, *qo1b, *qo2w, *qo2b;
  const float *av1w, *av1b, *av2w, *av2b, *fv1w, *fv1b, *fv2w, *fv2b;
  float *out0, *out1, *out2;
};

// ---- staging helpers (coalesced global -> LDS) ----
__device__ __forceinline__ void cp_f32(float* dst, const float* src, int n, int tid) {
  for (int k = tid; k < n; k += 256) dst[k] = src[k];
}
template<int COLS, int PAD>
__device__ __forceinline__ void cp_pad(float* dst, const float* src, int n, int tid) {
  for (int k = tid; k < n; k += 256) dst[(k / COLS) * PAD + (k % COLS)] = src[k];
}
__device__ __forceinline__ void cp_h(f16* dst, const float* src, int n, int tid) {
  h2* d2 = (h2*)dst;
  const float2* s2 = (const float2*)src;
  for (int k = tid; k < n / 2; k += 256) { float2 v = s2[k]; d2[k] = h2{(f16)v.x, (f16)v.y}; }
}
__device__ __forceinline__ void cp_t68(float* dst, const float* src, int tid) {
  // src [64][64] row-major (o2,o) -> dst[o*68 + o2]
  for (int k = tid; k < 4096; k += 256) { int o2 = k >> 6, o = k & 63; dst[o * 68 + o2] = src[k]; }
}
__device__ __forceinline__ void cp_fv2t(float* dst, const float* src, int tid) {
  // src [8][64] (v,o) -> dst[o*8 + v]
  for (int k = tid; k < 512; k += 256) { int v = k >> 6, o = k & 63; dst[o * 8 + v] = src[k]; }
}

// mini-MLP layer: 16 rows x 64 outs, thread (r=tid>>4, ob=tid&15) does o = ob+16*oo
__device__ __forceinline__ void mini64(const float* W /*[64][68]*/, const float* bias,
                                       const float* xrow, float* outrow, bool relu, int ob) {
  float acc[4];
#pragma unroll
  for (int oo = 0; oo < 4; oo++) acc[oo] = bias[ob + 16 * oo];
  for (int d = 0; d < 64; d += 4) {
    const float4 xv = *(const float4*)(xrow + d);
#pragma unroll
    for (int oo = 0; oo < 4; oo++) {
      const float4 wv = *(const float4*)(W + (ob + 16 * oo) * 68 + d);
      acc[oo] += wv.x * xv.x + wv.y * xv.y + wv.z * xv.z + wv.w * xv.w;
    }
  }
#pragma unroll
  for (int oo = 0; oo < 4; oo++) {
    float v = acc[oo];
    if (relu) v = lrelu(v);
    outrow[ob + 16 * oo] = v;
  }
}

__global__ __launch_bounds__(256, 1) void critic_kernel(P p) {
  __shared__ SMem s;
  const int tid = threadIdx.x;
  const int b = blockIdx.x;
  const int i16 = tid >> 4, j16 = tid & 15;

  // ---- phase 1: load batch inputs + stage kw1 ----
  cp_pad<64, 68>(&s.obs[0][0], p.obs + (size_t)b * 1024, 1024, tid);
  cp_f32(&s.pi[0][0], p.pol + (size_t)b * 128, 128, tid);
  cp_f32(&s.act[0][0], p.act + (size_t)b * 128, 128, tid);
  cp_pad<64, 68>(s.wb.f, p.kw1w, 4096, tid);
  cp_f32(s.wb.f + 4352, p.kw1b, 64, tid);
  __syncthreads();

  // ---- key_z ----
  mini64(s.wb.f, s.wb.f + 4352, &s.obs[i16][0], &s.u.r1.ht[i16][0], true, j16);
  __syncthreads();
  cp_pad<64, 68>(s.wb.f, p.kw2w, 4096, tid);
  cp_f32(s.wb.f + 4352, p.kw2b, 64, tid);
  __syncthreads();
  mini64(s.wb.f, s.wb.f + 4352, &s.u.r1.ht[i16][0], &s.u.r1.a1[i16][0], false, j16);
  __syncthreads();

  // ---- query_z ----
  cp_pad<64, 68>(s.wb.f, p.qw1w, 4096, tid);
  cp_f32(s.wb.f + 4352, p.qw1b, 64, tid);
  __syncthreads();
  mini64(s.wb.f, s.wb.f + 4352, &s.obs[i16][0], &s.u.r1.ht[i16][0], true, j16);
  __syncthreads();
  cp_pad<64, 68>(s.wb.f, p.qw2w, 4096, tid);
  cp_f32(s.wb.f + 4352, p.qw2b, 64, tid);
  __syncthreads();
  mini64(s.wb.f, s.wb.f + 4352, &s.u.r1.ht[i16][0], &s.u.r1.a2[i16][0], false, j16);
  __syncthreads();

  // ---- score, sigmoid w ; stage ko1 ----
  {
    float sc = 0.f;
#pragma unroll
    for (int d = 0; d < 64; d += 4) {
      const float4 qv = *(const float4*)(&s.u.r1.a2[i16][d]);  // query_z[i]
      const float4 kv = *(const float4*)(&s.u.r1.a1[j16][d]);  // key_z[j]
      sc += qv.x * kv.x + qv.y * kv.y + qv.z * kv.z + qv.w * kv.w;
    }
    const float w = 1.f / (1.f + expf(-sc * 0.125f));
    s.wsig[i16][j16] = w;
    p.out1[(size_t)b * 256 + tid] = w;   // weight_z
  }
  cp_pad<72, 76>(s.wb.f, p.ko1w, 4608, tid);
  cp_f32(s.wb.f + 64 * 76, p.ko1b, 64, tid);
  __syncthreads();

  // ---- key_o layer 1 (x = [obs[r], z(r,r)]) ----
  {
    const int r = i16, ob = j16;
    float acc[4];
#pragma unroll
    for (int oo = 0; oo < 4; oo++) acc[oo] = s.wb.f[64 * 76 + ob + 16 * oo];
    for (int d = 0; d < 64; d += 4) {
      const float4 xv = *(const float4*)(&s.obs[r][d]);
#pragma unroll
      for (int oo = 0; oo < 4; oo++) {
        const float4 wv = *(const float4*)(&s.wb.f[(ob + 16 * oo) * 76 + d]);
        acc[oo] += wv.x * xv.x + wv.y * xv.y + wv.z * xv.z + wv.w * xv.w;
      }
    }
    const float wrr = s.wsig[r][r];
#pragma unroll
    for (int c = 0; c < 8; c++) {
      const float zc = wrr * s.act[r][c] + (1.f - wrr) * s.pi[r][c];
#pragma unroll
      for (int oo = 0; oo < 4; oo++) acc[oo] += s.wb.f[(ob + 16 * oo) * 76 + 64 + c] * zc;
    }
#pragma unroll
    for (int oo = 0; oo < 4; oo++) s.u.r1.ht[r][ob + 16 * oo] = lrelu(acc[oo]);
  }
  __syncthreads();
  cp_pad<64, 68>(s.wb.f, p.ko2w, 4096, tid);
  cp_f32(s.wb.f + 4352, p.ko2b, 64, tid);
  __syncthreads();
  mini64(s.wb.f, s.wb.f + 4352, &s.u.r1.ht[i16][0], &s.u.r1.a3[i16][0], false, j16); // key_o
  __syncthreads();

  // ---- ck = W2qo^T . key_o ; c0 = key_o . b2qo ----
  cp_t68(s.wb.f, p.qo2w, tid);
  cp_f32(s.wb.f + 4352, p.qo2b, 64, tid);
  __syncthreads();
  {
    const int r = i16, ob = j16;
    float acc[4] = {0.f, 0.f, 0.f, 0.f};
    for (int d = 0; d < 64; d += 4) {
      const float4 xv = *(const float4*)(&s.u.r1.a3[r][d]);
#pragma unroll
      for (int oo = 0; oo < 4; oo++) {
        const float4 wv = *(const float4*)(&s.wb.f[(ob + 16 * oo) * 68 + d]);
        acc[oo] += wv.x * xv.x + wv.y * xv.y + wv.z * xv.z + wv.w * xv.w;
      }
    }
#pragma unroll
    for (int oo = 0; oo < 4; oo++) s.u.r1.a1[r][ob + 16 * oo] = acc[oo];
    if (ob == 0) {
      float c = 0.f;
      for (int d = 0; d < 64; d++) c += s.u.r1.a3[r][d] * s.wb.f[64 * 68 + d];
      s.c0[r] = c;
    }
  }
  __syncthreads();

  // ---- query_o layer1 fused with score_o (layer2 folded into ck) ----
  cp_f32(s.wb.f, p.qo1w, 4608, tid);      // [64][72], uniform broadcast reads
  cp_f32(s.wb.f + 4608, p.qo1b, 64, tid);
  __syncthreads();
  {
    const int i = i16, j = j16;
    float x[72];
#pragma unroll
    for (int q = 0; q < 16; q++) {
      const float4 v = *(const float4*)(&s.obs[j][4 * q]);
      x[4 * q] = v.x; x[4 * q + 1] = v.y; x[4 * q + 2] = v.z; x[4 * q + 3] = v.w;
    }
    const float wij = s.wsig[i][j];
#pragma unroll
    for (int c = 0; c < 8; c++) x[64 + c] = wij * s.act[j][c] + (1.f - wij) * s.pi[j][c];
    float sc = s.c0[i];
    for (int o = 0; o < 64; o++) {
      const float* wr = &s.wb.f[o * 72];
      float a0 = 0.f, a1 = 0.f, a2v = 0.f, a3v = 0.f;
#pragma unroll
      for (int d = 0; d < 72; d += 4) {
        const float4 wv = *(const float4*)(wr + d);
        a0 += wv.x * x[d]; a1 += wv.y * x[d + 1]; a2v += wv.z * x[d + 2]; a3v += wv.w * x[d + 3];
      }
      float hv = a0 + a1 + a2v + a3v + s.wb.f[4608 + o];
      hv = lrelu(hv);
      sc += s.u.r1.a1[i][o] * hv;
    }
    float yv = sc * 0.125f;
    yv = fminf(fmaxf(yv, -5.f), 5.f);
    s.u.r1.a2[i][j] = expf(yv);   // e = exp(clip(score_o/8))
  }
  __syncthreads();

  // ---- softmax over j of e ----
  float ex;
  {
    float m = s.u.r1.a2[i16][0];
#pragma unroll
    for (int j = 1; j < 16; j++) m = fmaxf(m, s.u.r1.a2[i16][j]);
    ex = expf(s.u.r1.a2[i16][j16] - m);
    s.wo[i16][j16] = ex;
  }
  __syncthreads();
  float den = 0.f;
#pragma unroll
  for (int j = 0; j < 16; j++) den += s.wo[i16][j];
  __syncthreads();
  s.wo[i16][j16] = ex / den;
  // stage av weights (fp16) + biases (fp32)
  cp_h(s.wb.h, p.av1w, 4608, tid);          // av1 [64][72]
  cp_h(s.wb.h + 4608, p.av2w, 4096, tid);   // av2 [64][64] (o2,o)
  cp_f32(s.wb.f + 4352, p.av1b, 64, tid);
  cp_f32(s.wb.f + 4416, p.av2b, 64, tid);
  __syncthreads();

  // ---- AO rows (256) : mlp_av(obs_z[i,j]) -> striped fp16 ----
  {
    const int i = i16, j = j16;
    h2 x2[36];
#pragma unroll
    for (int q = 0; q < 16; q++) {
      const float4 v = *(const float4*)(&s.obs[j][4 * q]);
      x2[2 * q] = h2{(f16)v.x, (f16)v.y};
      x2[2 * q + 1] = h2{(f16)v.z, (f16)v.w};
    }
    const float wij = s.wsig[i][j];
#pragma unroll
    for (int c = 0; c < 4; c++) {
      const float z0 = wij * s.act[j][2 * c] + (1.f - wij) * s.pi[j][2 * c];
      const float z1 = wij * s.act[j][2 * c + 1] + (1.f - wij) * s.pi[j][2 * c + 1];
      x2[32 + c] = h2{(f16)z0, (f16)z1};
    }
    float y[64];
#pragma unroll
    for (int o = 0; o < 64; o++) y[o] = s.wb.f[4416 + o];   // b2
    for (int op = 0; op < 32; op++) {
      f16 hp[2];
#pragma unroll
      for (int t = 0; t < 2; t++) {
        const int o = 2 * op + t;
        const float4* wq = (const float4*)(s.wb.h + o * 72);
        float a0 = 0.f, a1 = 0.f, a2v = 0.f, a3v = 0.f;
#pragma unroll
        for (int q = 0; q < 9; q++) {
          const float4 w4 = wq[q];
          a0 = fdot2f(as_h2(w4.x), x2[4 * q], a0);
          a1 = fdot2f(as_h2(w4.y), x2[4 * q + 1], a1);
          a2v = fdot2f(as_h2(w4.z), x2[4 * q + 2], a2v);
          a3v = fdot2f(as_h2(w4.w), x2[4 * q + 3], a3v);
        }
        hp[t] = (f16)lrelu(a0 + a1 + a2v + a3v + s.wb.f[4352 + o]);
      }
      const h2 hh = h2{hp[0], hp[1]};
      const h2* w2p = ((const h2*)(s.wb.h + 4608)) + op;
#pragma unroll
      for (int o2 = 0; o2 < 64; o2++) y[o2] = fdot2f(w2p[o2 * 32], hh, y[o2]);
    }
#pragma unroll
    for (int pc = 0; pc < 32; pc++)
      s.u.r2.AOs[pc][tid] = h2{(f16)y[2 * pc], (f16)y[2 * pc + 1]};
  }
  // ---- AP layer 1 (16 rows, mini, x = [obs[r], pi[r]]) ----
  {
    const int r = i16, ob = j16;
    h2 xp[36];
#pragma unroll
    for (int q = 0; q < 16; q++) {
      const float4 v = *(const float4*)(&s.obs[r][4 * q]);
      xp[2 * q] = h2{(f16)v.x, (f16)v.y};
      xp[2 * q + 1] = h2{(f16)v.z, (f16)v.w};
    }
#pragma unroll
    for (int c = 0; c < 4; c++) xp[32 + c] = h2{(f16)s.pi[r][2 * c], (f16)s.pi[r][2 * c + 1]};
#pragma unroll
    for (int oo = 0; oo < 4; oo++) {
      const int o = ob + 16 * oo;
      const float4* wq = (const float4*)(s.wb.h + o * 72);
      float a0 = 0.f, a1 = 0.f, a2v = 0.f, a3v = 0.f;
#pragma unroll
      for (int q = 0; q < 9; q++) {
        const float4 w4 = wq[q];
        a0 = fdot2f(as_h2(w4.x), xp[4 * q], a0);
        a1 = fdot2f(as_h2(w4.y), xp[4 * q + 1], a1);
        a2v = fdot2f(as_h2(w4.z), xp[4 * q + 2], a2v);
        a3v = fdot2f(as_h2(w4.w), xp[4 * q + 3], a3v);
      }
      s.htap[r][o] = (f16)lrelu(a0 + a1 + a2v + a3v + s.wb.f[4352 + o]);
    }
  }
  __syncthreads();
  // ---- AP layer 2 (mini): outs o2 = 4*ob + c ----
  {
    const int r = i16, ob = j16;
    const h2* hp = (const h2*)(&s.htap[r][0]);
    float acc[4];
#pragma unroll
    for (int c = 0; c < 4; c++) acc[c] = s.wb.f[4416 + 4 * ob + c];
    for (int pq = 0; pq < 32; pq++) {
      const h2 hv = hp[pq];
#pragma unroll
      for (int c = 0; c < 4; c++) {
        const h2 wv = ((const h2*)(s.wb.h + 4608))[(4 * ob + c) * 32 + pq];
        acc[c] = fdot2f(wv, hv, acc[c]);
      }
    }
    s.u.r2.APs[2 * ob][r] = h2{(f16)acc[0], (f16)acc[1]};
    s.u.r2.APs[2 * ob + 1][r] = h2{(f16)acc[2], (f16)acc[3]};
  }
  __syncthreads();

  // ---- stage fv weights ----
  cp_h(s.wb.h, p.fv1w, 8192, tid);          // fv1 [64][128] fp16
  cp_f32(s.wb.f + 4096, p.fv1b, 64, tid);
  cp_fv2t(s.wb.f + 4160, p.fv2w, tid);      // fv2^T [64][8] fp32
  cp_f32(s.wb.f + 4672, p.fv2b, 8, tid);
  __syncthreads();

  // ---- mixed + value head + outputs ----
  {
    const int i = i16, k = j16;
    h2 m2[32];
#pragma unroll
    for (int pc = 0; pc < 32; pc++) m2[pc] = h2{(f16)0.f, (f16)0.f};
    for (int j = 0; j < 16; j++) {
      const float wk = s.wo[k][j];
      const h2 wk2 = h2{(f16)wk, (f16)wk};
      const int r = 16 * i + j;
#pragma unroll
      for (int pc = 0; pc < 32; pc++) m2[pc] = s.u.r2.AOs[pc][r] * wk2 + m2[pc];
    }
    {
      const float wkk = s.wo[k][k];
      const h2 wkk2 = h2{(f16)wkk, (f16)wkk};
      const int rk = 16 * i + k;
#pragma unroll
      for (int pc = 0; pc < 32; pc++)
        m2[pc] = (s.u.r2.APs[pc][k] - s.u.r2.AOs[pc][rk]) * wkk2 + m2[pc];
    }
    h2 x2[64];
    const h2 s16v = h2{(f16)0.0625f, (f16)0.0625f};
#pragma unroll
    for (int pc = 0; pc < 32; pc++) x2[pc] = s.u.r2.AOs[pc][17 * k];  // attn_src[k]
#pragma unroll
    for (int pc = 0; pc < 32; pc++) x2[32 + pc] = m2[pc] * s16v;      // mixed (mean /16)
    float y[8];
#pragma unroll
    for (int v = 0; v < 8; v++) y[v] = s.wb.f[4672 + v];
    for (int o = 0; o < 64; o++) {
      const float4* wq = (const float4*)(s.wb.h + o * 128);
      float a0 = 0.f, a1 = 0.f, a2v = 0.f, a3v = 0.f;
#pragma unroll
      for (int q = 0; q < 16; q++) {
        const float4 w4 = wq[q];
        a0 = fdot2f(as_h2(w4.x), x2[4 * q], a0);
        a1 = fdot2f(as_h2(w4.y), x2[4 * q + 1], a1);
        a2v = fdot2f(as_h2(w4.z), x2[4 * q + 2], a2v);
        a3v = fdot2f(as_h2(w4.w), x2[4 * q + 3], a3v);
      }
      float hv = lrelu(a0 + a1 + a2v + a3v + s.wb.f[4096 + o]);
      const float* w2 = &s.wb.f[4160 + o * 8];
#pragma unroll
      for (int v = 0; v < 8; v++) y[v] += w2[v] * hv;
    }
    float* o0 = p.out0 + ((size_t)b * 256 + tid) * 8;
    *(float4*)(o0) = make_float4(y[0], y[1], y[2], y[3]);
    *(float4*)(o0 + 4) = make_float4(y[4], y[5], y[6], y[7]);
    float* o2p = p.out2 + ((size_t)b * 256 + tid) * 16;
#pragma unroll
    for (int jq = 0; jq < 4; jq++)
      *(float4*)(o2p + 4 * jq) = make_float4(s.wo[k][4 * jq], s.wo[k][4 * jq + 1],
                                             s.wo[k][4 * jq + 2], s.wo[k][4 * jq + 3]);
  }
}

extern "C" void kernel_launch(void* const* d_in, const int* in_sizes, int n_in,
                              void* d_out, int out_size, void* d_ws, size_t ws_size,
                              hipStream_t stream) {
  P p;
  p.obs = (const float*)d_in[0];
  p.pol = (const float*)d_in[1];
  p.act = (const float*)d_in[2];
  p.kw1w = (const float*)d_in[3];  p.kw1b = (const float*)d_in[4];
  p.kw2w = (const float*)d_in[5];  p.kw2b = (const float*)d_in[6];
  p.qw1w = (const float*)d_in[7];  p.qw1b = (const float*)d_in[8];
  p.qw2w = (const float*)d_in[9];  p.qw2b = (const float*)d_in[10];
  p.ko1w = (const float*)d_in[11]; p.ko1b = (const float*)d_in[12];
  p.ko2w = (const float*)d_in[13]; p.ko2b = (const float*)d_in[14];
  p.qo1w = (const float*)d_in[15]; p.qo1b = (const float*)d_in[16];
  p.qo2w = (const float*)d_in[17]; p.qo2b = (const float*)d_in[18];
  p.av1w = (const float*)d_in[19]; p.av1b = (const float*)d_in[20];
  p.av2w = (const float*)d_in[21]; p.av2b = (const float*)d_in[22];
  p.fv1w = (const float*)d_in[23]; p.fv1b = (const float*)d_in[24];
  p.fv2w = (const float*)d_in[25]; p.fv2b = (const float*)d_in[26];

  const int Bn = in_sizes[0] / (A_ * DOBS_);   // 128
  p.out0 = (float*)d_out;
  p.out1 = p.out0 + (size_t)Bn * A_ * A_ * NA_;
  p.out2 = p.out1 + (size_t)Bn * A_ * A_;

  hipLaunchKernelGGL(critic_kernel, dim3(Bn), dim3(256), 0, stream, p);
}

// Round 2
// 163.822 us; speedup vs baseline: 1.3885x; 1.3885x over previous
//
#include <hip/hip_runtime.h>

#define A_ 16
#define NA_ 8
#define DOBS_ 64

typedef _Float16 f16;
typedef f16 h2 __attribute__((ext_vector_type(2)));

__device__ __forceinline__ float fdot2f(h2 a, h2 b, float c) {
  return __builtin_amdgcn_fdot2(a, b, c, false);
}
__device__ __forceinline__ h2 as_h2(float x) { return __builtin_bit_cast(h2, x); }
__device__ __forceinline__ h2 shfl_h2(h2 v, int mask) {
  int iv = __builtin_bit_cast(int, v);
  iv = __shfl_xor(iv, mask);
  return __builtin_bit_cast(h2, iv);
}
__device__ __forceinline__ float lrelu(float x) { return x > 0.f ? x : 0.01f * x; }

__device__ __forceinline__ float dot64(const float* w, const float* x) {
  float a0 = 0.f, a1 = 0.f, a2 = 0.f, a3 = 0.f;
#pragma unroll
  for (int d = 0; d < 64; d += 4) {
    const float4 wv = *(const float4*)(w + d);
    const float4 xv = *(const float4*)(x + d);
    a0 += wv.x * xv.x; a1 += wv.y * xv.y; a2 += wv.z * xv.z; a3 += wv.w * xv.w;
  }
  return (a0 + a1) + (a2 + a3);
}

struct PA { float obs[16][68]; float ht[16][68]; float a1[16][68]; float a2[16][68]; float a3[16][68]; };

struct alignas(16) SMem {
  float pi[16][8];      // 512
  float act[16][8];     // 512
  float wsig[16][16];   // 1024
  float wo[16][16];     // 1024
  float c0[16];         // 64
  float wz8[64][8];     // 2048  (z-part of qo1, then av1)
  h2    APs[32][17];    // 2176
  float GF[1088];       // 4352  (Gt -> Gavt [o*16+j], then Ft [o*17+k])
  union { PA pa; h2 AOs[32][257]; } u;          // 32896
  union { float f[4928]; f16 h[9856]; } wb;     // 19712
};  // total 64320 B

struct P {
  const float *obs, *pol, *act;
  const float *kw1w, *kw1b, *kw2w, *kw2b, *qw1w, *qw1b, *qw2w, *qw2b;
  const float *ko1w, *ko1b, *ko2w, *ko2b, *qo1w, *qo1b, *qo2w, *qo2b;
  const float *av1w, *av1b, *av2w, *av2b, *fv1w, *fv1b, *fv2w, *fv2b;
  float *out0, *out1, *out2;
};

__global__ __launch_bounds__(1024) void critic_kernel(P p) {
  __shared__ SMem s;
  const int tid = threadIdx.x;
  const int b = blockIdx.x;
  const int r16 = tid & 15, o64 = tid >> 4;   // mini-phase mapping (weight reads broadcast)
  const int q = tid >> 2, g = tid & 3;        // quad-phase mapping
  const int qi = q >> 4, qj = q & 15;

  // ---------- phase 1: inputs + kw1 ----------
  for (int k = tid; k < 1024; k += 1024) s.u.pa.obs[k >> 6][k & 63] = p.obs[(size_t)b * 1024 + k];
  if (tid < 128) s.pi[tid >> 3][tid & 7] = p.pol[(size_t)b * 128 + tid];
  else if (tid < 256) { int k = tid - 128; s.act[k >> 3][k & 7] = p.act[(size_t)b * 128 + k]; }
  for (int k = tid; k < 4096; k += 1024) s.wb.f[(k >> 6) * 68 + (k & 63)] = p.kw1w[k];
  if (tid < 64) s.wb.f[4352 + tid] = p.kw1b[tid];
  __syncthreads();

  // ---------- kw: layer1 ----------
  s.u.pa.ht[r16][o64] = lrelu(dot64(&s.wb.f[o64 * 68], &s.u.pa.obs[r16][0]) + s.wb.f[4352 + o64]);
  __syncthreads();
  for (int k = tid; k < 4096; k += 1024) s.wb.f[(k >> 6) * 68 + (k & 63)] = p.kw2w[k];
  if (tid < 64) s.wb.f[4352 + tid] = p.kw2b[tid];
  __syncthreads();
  s.u.pa.a1[r16][o64] = dot64(&s.wb.f[o64 * 68], &s.u.pa.ht[r16][0]) + s.wb.f[4352 + o64]; // key_z
  __syncthreads();

  // ---------- qw ----------
  for (int k = tid; k < 4096; k += 1024) s.wb.f[(k >> 6) * 68 + (k & 63)] = p.qw1w[k];
  if (tid < 64) s.wb.f[4352 + tid] = p.qw1b[tid];
  __syncthreads();
  s.u.pa.ht[r16][o64] = lrelu(dot64(&s.wb.f[o64 * 68], &s.u.pa.obs[r16][0]) + s.wb.f[4352 + o64]);
  __syncthreads();
  for (int k = tid; k < 4096; k += 1024) s.wb.f[(k >> 6) * 68 + (k & 63)] = p.qw2w[k];
  if (tid < 64) s.wb.f[4352 + tid] = p.qw2b[tid];
  __syncthreads();
  s.u.pa.a2[r16][o64] = dot64(&s.wb.f[o64 * 68], &s.u.pa.ht[r16][0]) + s.wb.f[4352 + o64]; // query_z
  __syncthreads();

  // ---------- score/sigmoid + stage ko1 ----------
  for (int k = tid; k < 4608; k += 1024) s.wb.f[(k / 72) * 76 + (k % 72)] = p.ko1w[k];
  if (tid < 64) s.wb.f[64 * 76 + tid] = p.ko1b[tid];
  if (tid < 256) {
    const int i = tid >> 4, j = tid & 15;
    const float sc = dot64(&s.u.pa.a2[i][0], &s.u.pa.a1[j][0]);
    const float w = 1.f / (1.f + __expf(-sc * 0.125f));
    s.wsig[i][j] = w;
    p.out1[(size_t)b * 256 + tid] = w;
  }
  __syncthreads();

  // ---------- ko layer1 (x = [obs[r], z(r,r)]) ----------
  {
    const float* w = &s.wb.f[o64 * 76];
    float acc = dot64(w, &s.u.pa.obs[r16][0]);
    const float wrr = s.wsig[r16][r16];
#pragma unroll
    for (int c = 0; c < 8; c++) {
      const float zc = s.pi[r16][c] + wrr * (s.act[r16][c] - s.pi[r16][c]);
      acc += w[64 + c] * zc;
    }
    s.u.pa.ht[r16][o64] = lrelu(acc + s.wb.f[64 * 76 + o64]);
  }
  __syncthreads();
  for (int k = tid; k < 4096; k += 1024) s.wb.f[(k >> 6) * 68 + (k & 63)] = p.ko2w[k];
  if (tid < 64) s.wb.f[4352 + tid] = p.ko2b[tid];
  __syncthreads();
  s.u.pa.a3[r16][o64] = dot64(&s.wb.f[o64 * 68], &s.u.pa.ht[r16][0]) + s.wb.f[4352 + o64]; // key_o
  __syncthreads();

  // ---------- ck = qo2^T . key_o ; c0 ----------
  for (int k = tid; k < 4096; k += 1024) { const int o2 = k >> 6, o = k & 63; s.wb.f[o * 68 + o2] = p.qo2w[k]; }
  if (tid < 64) s.wb.f[4352 + tid] = p.qo2b[tid];
  __syncthreads();
  s.u.pa.a1[r16][o64] = dot64(&s.wb.f[o64 * 68], &s.u.pa.a3[r16][0]);   // ck
  if (tid < 16) s.c0[tid] = dot64(&s.u.pa.a3[tid][0], &s.wb.f[4352]);
  __syncthreads();

  // ---------- stage qo1, precompute Gt + wz8 ----------
  for (int k = tid; k < 4608; k += 1024) s.wb.f[k] = p.qo1w[k];
  if (tid < 64) s.wb.f[4608 + tid] = p.qo1b[tid];
  __syncthreads();
  s.GF[o64 * 16 + r16] = dot64(&s.wb.f[o64 * 72], &s.u.pa.obs[r16][0]) + s.wb.f[4608 + o64];
  for (int k = tid; k < 512; k += 1024) s.wz8[0][k] = s.wb.f[(k >> 3) * 72 + 64 + (k & 7)];
  __syncthreads();

  // ---------- qo-score (quad per pair) ----------
  {
    const float wij = s.wsig[qi][qj];
    float z[8];
#pragma unroll
    for (int c = 0; c < 8; c++) z[c] = s.pi[qj][c] + wij * (s.act[qj][c] - s.pi[qj][c]);
    float sc = 0.f;
#pragma unroll
    for (int t = 0; t < 16; t++) {
      const int o = g * 16 + t;
      const float4 wa = *(const float4*)(&s.wz8[o][0]);
      const float4 wbv = *(const float4*)(&s.wz8[o][4]);
      float hv = s.GF[o * 16 + qj]
        + wa.x * z[0] + wa.y * z[1] + wa.z * z[2] + wa.w * z[3]
        + wbv.x * z[4] + wbv.y * z[5] + wbv.z * z[6] + wbv.w * z[7];
      hv = lrelu(hv);
      sc += s.u.pa.a1[qi][o] * hv;
    }
    sc += __shfl_xor(sc, 1);
    sc += __shfl_xor(sc, 2);
    if (g == 0) {
      float yv = (sc + s.c0[qi]) * 0.125f;
      yv = fminf(fmaxf(yv, -5.f), 5.f);
      s.u.pa.a2[qi][qj] = __expf(yv);     // e = exp(clip(score_o/8))
    }
  }
  __syncthreads();

  // ---------- softmax + stage av1 ----------
  for (int k = tid; k < 4608; k += 1024) s.wb.f[k] = p.av1w[k];
  if (tid < 64) s.wb.f[4608 + tid] = p.av1b[tid];
  if (tid < 256) {
    const int i = tid >> 4, j = tid & 15;
    float e[16]; float m = -1e30f;
#pragma unroll
    for (int jj = 0; jj < 16; jj++) { e[jj] = s.u.pa.a2[i][jj]; m = fmaxf(m, e[jj]); }
    float den = 0.f;
#pragma unroll
    for (int jj = 0; jj < 16; jj++) den += __expf(e[jj] - m);
    s.wo[i][j] = __expf(e[j] - m) / den;
  }
  __syncthreads();

  // ---------- Gavt + wz8 (av1) ----------
  s.GF[o64 * 16 + r16] = dot64(&s.wb.f[o64 * 72], &s.u.pa.obs[r16][0]) + s.wb.f[4608 + o64];
  for (int k = tid; k < 512; k += 1024) s.wz8[0][k] = s.wb.f[(k >> 3) * 72 + 64 + (k & 7)];
  __syncthreads();

  // ---------- stage av2 (f16) ----------
  { h2* d2 = (h2*)s.wb.h; const float2* s2 = (const float2*)p.av2w;
    for (int k = tid; k < 2048; k += 1024) { float2 v = s2[k]; d2[k] = h2{(f16)v.x, (f16)v.y}; } }
  if (tid < 64) s.wb.f[2048 + tid] = p.av2b[tid];
  __syncthreads();

  // ---------- AO (all 256 rows) + AP (rows 0..15, wave 0) ----------
  {
    const float wij = s.wsig[qi][qj];
    float z[8];
#pragma unroll
    for (int c = 0; c < 8; c++) z[c] = s.pi[qj][c] + wij * (s.act[qj][c] - s.pi[qj][c]);
    h2 hh[8];
#pragma unroll
    for (int e = 0; e < 8; e++) {
      float hv2[2];
#pragma unroll
      for (int t2 = 0; t2 < 2; t2++) {
        const int o = g * 16 + 2 * e + t2;
        const float4 wa = *(const float4*)(&s.wz8[o][0]);
        const float4 wbv = *(const float4*)(&s.wz8[o][4]);
        float hv = s.GF[o * 16 + qj]
          + wa.x * z[0] + wa.y * z[1] + wa.z * z[2] + wa.w * z[3]
          + wbv.x * z[4] + wbv.y * z[5] + wbv.z * z[6] + wbv.w * z[7];
        hv2[t2] = lrelu(hv);
      }
      hh[e] = h2{(f16)hv2[0], (f16)hv2[1]};
    }
    float y[16];
#pragma unroll
    for (int t = 0; t < 16; t++) y[t] = s.wb.f[2048 + g * 16 + t];
#pragma unroll
    for (int ss = 0; ss < 4; ss++) {
      h2 hs[8];
#pragma unroll
      for (int e = 0; e < 8; e++) hs[e] = (ss == 0) ? hh[e] : shfl_h2(hh[e], ss);
      const int dblk = g ^ ss;
      const h2* w2b = ((const h2*)s.wb.h) + dblk * 8;
#pragma unroll
      for (int t = 0; t < 16; t++) {
        const int o2 = g * 16 + t;
        const float4 wA = *(const float4*)(w2b + o2 * 32);
        const float4 wB = *(const float4*)(w2b + o2 * 32 + 4);
        y[t] = fdot2f(as_h2(wA.x), hs[0], y[t]);
        y[t] = fdot2f(as_h2(wA.y), hs[1], y[t]);
        y[t] = fdot2f(as_h2(wA.z), hs[2], y[t]);
        y[t] = fdot2f(as_h2(wA.w), hs[3], y[t]);
        y[t] = fdot2f(as_h2(wB.x), hs[4], y[t]);
        y[t] = fdot2f(as_h2(wB.y), hs[5], y[t]);
        y[t] = fdot2f(as_h2(wB.z), hs[6], y[t]);
        y[t] = fdot2f(as_h2(wB.w), hs[7], y[t]);
      }
    }
#pragma unroll
    for (int e = 0; e < 8; e++)
      s.u.AOs[g * 8 + e][q] = h2{(f16)y[2 * e], (f16)y[2 * e + 1]};

    if (q < 16) {  // AP rows, wave 0 fully active
      const int r = q;
      h2 hp[8];
#pragma unroll
      for (int e = 0; e < 8; e++) {
        float hv2[2];
#pragma unroll
        for (int t2 = 0; t2 < 2; t2++) {
          const int o = g * 16 + 2 * e + t2;
          const float4 wa = *(const float4*)(&s.wz8[o][0]);
          const float4 wbv = *(const float4*)(&s.wz8[o][4]);
          float hv = s.GF[o * 16 + r]
            + wa.x * s.pi[r][0] + wa.y * s.pi[r][1] + wa.z * s.pi[r][2] + wa.w * s.pi[r][3]
            + wbv.x * s.pi[r][4] + wbv.y * s.pi[r][5] + wbv.z * s.pi[r][6] + wbv.w * s.pi[r][7];
          hv2[t2] = lrelu(hv);
        }
        hp[e] = h2{(f16)hv2[0], (f16)hv2[1]};
      }
      float yp[16];
#pragma unroll
      for (int t = 0; t < 16; t++) yp[t] = s.wb.f[2048 + g * 16 + t];
#pragma unroll
      for (int ss = 0; ss < 4; ss++) {
        h2 hs[8];
#pragma unroll
        for (int e = 0; e < 8; e++) hs[e] = (ss == 0) ? hp[e] : shfl_h2(hp[e], ss);
        const int dblk = g ^ ss;
        const h2* w2b = ((const h2*)s.wb.h) + dblk * 8;
#pragma unroll
        for (int t = 0; t < 16; t++) {
          const int o2 = g * 16 + t;
          const float4 wA = *(const float4*)(w2b + o2 * 32);
          const float4 wB = *(const float4*)(w2b + o2 * 32 + 4);
          yp[t] = fdot2f(as_h2(wA.x), hs[0], yp[t]);
          yp[t] = fdot2f(as_h2(wA.y), hs[1], yp[t]);
          yp[t] = fdot2f(as_h2(wA.z), hs[2], yp[t]);
          yp[t] = fdot2f(as_h2(wA.w), hs[3], yp[t]);
          yp[t] = fdot2f(as_h2(wB.x), hs[4], yp[t]);
          yp[t] = fdot2f(as_h2(wB.y), hs[5], yp[t]);
          yp[t] = fdot2f(as_h2(wB.z), hs[6], yp[t]);
          yp[t] = fdot2f(as_h2(wB.w), hs[7], yp[t]);
        }
      }
#pragma unroll
      for (int e = 0; e < 8; e++)
        s.APs[g * 8 + e][r] = h2{(f16)yp[2 * e], (f16)yp[2 * e + 1]};
    }
  }
  __syncthreads();

  // ---------- stage fv ----------
  { h2* d2 = (h2*)s.wb.h; const float2* s2 = (const float2*)p.fv1w;
    for (int k = tid; k < 4096; k += 1024) { float2 v = s2[k]; d2[k] = h2{(f16)v.x, (f16)v.y}; } }
  if (tid < 64) s.wb.f[4096 + tid] = p.fv1b[tid];
  for (int k = tid; k < 512; k += 1024) { const int v = k >> 6, o = k & 63; s.wb.f[4160 + o * 8 + v] = p.fv2w[k]; }
  if (tid < 8) s.wb.f[4672 + tid] = p.fv2b[tid];
  __syncthreads();

  // ---------- Ft[o][k] = fv1b[o] + fv1w[o][0:64] . attn_src[k] ----------
  {
    const int kk = r16, o = o64;
    const h2* wrow = ((const h2*)s.wb.h) + o * 64;
    float acc = s.wb.f[4096 + o];
#pragma unroll
    for (int pc = 0; pc < 32; pc += 4) {
      const float4 w4 = *(const float4*)(wrow + pc);
      acc = fdot2f(as_h2(w4.x), s.u.AOs[pc][kk * 17], acc);
      acc = fdot2f(as_h2(w4.y), s.u.AOs[pc + 1][kk * 17], acc);
      acc = fdot2f(as_h2(w4.z), s.u.AOs[pc + 2][kk * 17], acc);
      acc = fdot2f(as_h2(w4.w), s.u.AOs[pc + 3][kk * 17], acc);
    }
    s.GF[o * 17 + kk] = acc;
  }
  __syncthreads();

  // ---------- mixed + value head + outputs ----------
  {
    const int i = qi, k = qj, row = q;
    h2 m2[8];
#pragma unroll
    for (int e = 0; e < 8; e++) m2[e] = h2{(f16)0.f, (f16)0.f};
    for (int j = 0; j < 16; j++) {
      const float wkj = s.wo[k][j];
      const h2 wv = h2{(f16)wkj, (f16)wkj};
      const int rr = i * 16 + j;
#pragma unroll
      for (int e = 0; e < 8; e++) m2[e] = s.u.AOs[g * 8 + e][rr] * wv + m2[e];
    }
    {
      const float wkk = s.wo[k][k];
      const h2 wv = h2{(f16)wkk, (f16)wkk};
      const int rk = i * 16 + k;
#pragma unroll
      for (int e = 0; e < 8; e++) m2[e] = (s.APs[g * 8 + e][k] - s.u.AOs[g * 8 + e][rk]) * wv + m2[e];
    }
    const h2 s16 = h2{(f16)0.0625f, (f16)0.0625f};
#pragma unroll
    for (int e = 0; e < 8; e++) m2[e] = m2[e] * s16;

    float hv[16];
#pragma unroll
    for (int t = 0; t < 16; t++) hv[t] = s.GF[(g * 16 + t) * 17 + k];
#pragma unroll
    for (int ss = 0; ss < 4; ss++) {
      h2 ms[8];
#pragma unroll
      for (int e = 0; e < 8; e++) ms[e] = (ss == 0) ? m2[e] : shfl_h2(m2[e], ss);
      const int dblk = g ^ ss;
#pragma unroll
      for (int t = 0; t < 16; t++) {
        const int o = g * 16 + t;
        const h2* wrow = ((const h2*)s.wb.h) + o * 64 + 32 + dblk * 8;
        const float4 wA = *(const float4*)(wrow);
        const float4 wB = *(const float4*)(wrow + 4);
        hv[t] = fdot2f(as_h2(wA.x), ms[0], hv[t]);
        hv[t] = fdot2f(as_h2(wA.y), ms[1], hv[t]);
        hv[t] = fdot2f(as_h2(wA.z), ms[2], hv[t]);
        hv[t] = fdot2f(as_h2(wA.w), ms[3], hv[t]);
        hv[t] = fdot2f(as_h2(wB.x), ms[4], hv[t]);
        hv[t] = fdot2f(as_h2(wB.y), ms[5], hv[t]);
        hv[t] = fdot2f(as_h2(wB.z), ms[6], hv[t]);
        hv[t] = fdot2f(as_h2(wB.w), ms[7], hv[t]);
      }
    }
    float y[8];
#pragma unroll
    for (int v = 0; v < 8; v++) y[v] = (g == 0) ? s.wb.f[4672 + v] : 0.f;
#pragma unroll
    for (int t = 0; t < 16; t++) {
      const int o = g * 16 + t;
      const float h1 = lrelu(hv[t]);
      const float4 w2a = *(const float4*)(&s.wb.f[4160 + o * 8]);
      const float4 w2b = *(const float4*)(&s.wb.f[4160 + o * 8 + 4]);
      y[0] += w2a.x * h1; y[1] += w2a.y * h1; y[2] += w2a.z * h1; y[3] += w2a.w * h1;
      y[4] += w2b.x * h1; y[5] += w2b.y * h1; y[6] += w2b.z * h1; y[7] += w2b.w * h1;
    }
#pragma unroll
    for (int v = 0; v < 8; v++) { y[v] += __shfl_xor(y[v], 1); y[v] += __shfl_xor(y[v], 2); }
    *(float2*)(p.out0 + ((size_t)b * 256 + row) * 8 + 2 * g) = make_float2(y[2 * g], y[2 * g + 1]);
    *(float4*)(p.out2 + ((size_t)b * 256 + row) * 16 + 4 * g) =
        make_float4(s.wo[k][4 * g], s.wo[k][4 * g + 1], s.wo[k][4 * g + 2], s.wo[k][4 * g + 3]);
  }
}

extern "C" void kernel_launch(void* const* d_in, const int* in_sizes, int n_in,
                              void* d_out, int out_size, void* d_ws, size_t ws_size,
                              hipStream_t stream) {
  P p;
  p.obs = (const float*)d_in[0];
  p.pol = (const float*)d_in[1];
  p.act = (const float*)d_in[2];
  p.kw1w = (const float*)d_in[3];  p.kw1b = (const float*)d_in[4];
  p.kw2w = (const float*)d_in[5];  p.kw2b = (const float*)d_in[6];
  p.qw1w = (const float*)d_in[7];  p.qw1b = (const float*)d_in[8];
  p.qw2w = (const float*)d_in[9];  p.qw2b = (const float*)d_in[10];
  p.ko1w = (const float*)d_in[11]; p.ko1b = (const float*)d_in[12];
  p.ko2w = (const float*)d_in[13]; p.ko2b = (const float*)d_in[14];
  p.qo1w = (const float*)d_in[15]; p.qo1b = (const float*)d_in[16];
  p.qo2w = (const float*)d_in[17]; p.qo2b = (const float*)d_in[18];
  p.av1w = (const float*)d_in[19]; p.av1b = (const float*)d_in[20];
  p.av2w = (const float*)d_in[21]; p.av2b = (const float*)d_in[22];
  p.fv1w = (const float*)d_in[23]; p.fv1b = (const float*)d_in[24];
  p.fv2w = (const float*)d_in[25]; p.fv2b = (const float*)d_in[26];

  const int Bn = in_sizes[0] / (A_ * DOBS_);   // 128
  p.out0 = (float*)d_out;
  p.out1 = p.out0 + (size_t)Bn * A_ * A_ * NA_;
  p.out2 = p.out1 + (size_t)Bn * A_ * A_;

  hipLaunchKernelGGL(critic_kernel, dim3(Bn), dim3(1024), 0, stream, p);
}

// Round 3
// 144.694 us; speedup vs baseline: 1.5720x; 1.1322x over previous
//
#include <hip/hip_runtime.h>

#define A_ 16
#define NA_ 8
#define DOBS_ 64

typedef _Float16 f16;
typedef f16 h2 __attribute__((ext_vector_type(2)));
typedef f16 v8h __attribute__((ext_vector_type(8)));
typedef float v4f __attribute__((ext_vector_type(4)));

__device__ __forceinline__ float fdot2f(h2 a, h2 b, float c) {
  return __builtin_amdgcn_fdot2(a, b, c, false);
}
__device__ __forceinline__ float lrelu(float x) { return x > 0.f ? x : 0.01f * x; }

__device__ __forceinline__ float dot64(const float* w, const float* x) {
  float a0 = 0.f, a1 = 0.f, a2 = 0.f, a3 = 0.f;
#pragma unroll
  for (int d = 0; d < 64; d += 4) {
    const float4 wv = *(const float4*)(w + d);
    const float4 xv = *(const float4*)(x + d);
    a0 += wv.x * xv.x; a1 += wv.y * xv.y; a2 += wv.z * xv.z; a3 += wv.w * xv.w;
  }
  return (a0 + a1) + (a2 + a3);
}

struct P {
  const float *obs, *pol, *act;
  const float *kw1w, *kw1b, *kw2w, *kw2b, *qw1w, *qw1b, *qw2w, *qw2b;
  const float *ko1w, *ko1b, *ko2w, *ko2b, *qo1w, *qo1b, *qo2w, *qo2b;
  const float *av1w, *av1b, *av2w, *av2b, *fv1w, *fv1b, *fv2w, *fv2b;
  float *out0, *out1, *out2;
  float *wsig, *wo;   // workspace
};

// ======================= K1: fp32 front =======================

struct alignas(16) SMem1 {
  float obs[16][68];
  float pi[16][8], act[16][8];
  float wsig[16][16];
  float wo[16][16];
  float c0[16];
  float GF2[16 * 16 * 4];   // [t][j][g]  == G[o=g*16+t][j]
  float wz8n[16 * 32];      // [t][g*8+c] == qo1w[o=g*16+t][64+c]
  float ht[16][68];         // hidden scratch; later e[16][16]
  float a1[16][68];         // key_z -> ck
  float a2[16][68];         // query_z -> key_o
  struct { float w[64 * 68]; float b[64]; float z[64 * 8]; } W;
};

// thread tid<256 computes row r=tid>>4, outs o=(tid&15)+16*oo
__device__ __forceinline__ void mini256(const float* W, const float* bias, int addbias,
                                        const float (*X)[68], float (*Y)[68], int relu, int tid) {
  if (tid < 256) {
    const int r = tid >> 4, ob = tid & 15;
    float acc[4];
#pragma unroll
    for (int oo = 0; oo < 4; oo++) acc[oo] = addbias ? bias[ob + 16 * oo] : 0.f;
    for (int d = 0; d < 64; d += 4) {
      const float4 xv = *(const float4*)(&X[r][d]);
#pragma unroll
      for (int oo = 0; oo < 4; oo++) {
        const float4 wv = *(const float4*)(W + (ob + 16 * oo) * 68 + d);
        acc[oo] += wv.x * xv.x + wv.y * xv.y + wv.z * xv.z + wv.w * xv.w;
      }
    }
#pragma unroll
    for (int oo = 0; oo < 4; oo++) {
      float v = acc[oo];
      if (relu) v = lrelu(v);
      Y[r][ob + 16 * oo] = v;
    }
  }
}

__device__ __forceinline__ void stage68(float* dst, const float* src, int tid) {
  for (int k = tid; k < 4096; k += 1024) dst[(k >> 6) * 68 + (k & 63)] = src[k];
}

__global__ __launch_bounds__(1024) void critic_k1(P p) {
  __shared__ SMem1 s;
  const int tid = threadIdx.x;
  const int b = blockIdx.x;

  // ---- inputs + kw1 ----
  for (int k = tid; k < 1024; k += 1024) s.obs[k >> 6][k & 63] = p.obs[(size_t)b * 1024 + k];
  if (tid < 128) s.pi[tid >> 3][tid & 7] = p.pol[(size_t)b * 128 + tid];
  else if (tid < 256) { int k = tid - 128; s.act[k >> 3][k & 7] = p.act[(size_t)b * 128 + k]; }
  stage68(s.W.w, p.kw1w, tid);
  if (tid < 64) s.W.b[tid] = p.kw1b[tid];
  __syncthreads();
  mini256(s.W.w, s.W.b, 1, s.obs, s.ht, 1, tid);
  __syncthreads();
  stage68(s.W.w, p.kw2w, tid);
  if (tid < 64) s.W.b[tid] = p.kw2b[tid];
  __syncthreads();
  mini256(s.W.w, s.W.b, 1, s.ht, s.a1, 0, tid);   // key_z
  __syncthreads();
  stage68(s.W.w, p.qw1w, tid);
  if (tid < 64) s.W.b[tid] = p.qw1b[tid];
  __syncthreads();
  mini256(s.W.w, s.W.b, 1, s.obs, s.ht, 1, tid);
  __syncthreads();
  stage68(s.W.w, p.qw2w, tid);
  if (tid < 64) s.W.b[tid] = p.qw2b[tid];
  __syncthreads();
  mini256(s.W.w, s.W.b, 1, s.ht, s.a2, 0, tid);   // query_z
  __syncthreads();

  // ---- score + sigmoid ; stage ko1 (split) concurrently ----
  if (tid < 256) {
    const int i = tid >> 4, j = tid & 15;
    const float sc = dot64(&s.a2[i][0], &s.a1[j][0]);
    const float w = 1.f / (1.f + __expf(-sc * 0.125f));
    s.wsig[i][j] = w;
    p.out1[(size_t)b * 256 + tid] = w;
    p.wsig[(size_t)b * 256 + tid] = w;
  }
  for (int k = tid; k < 4096; k += 1024) { int o = k >> 6, c = k & 63; s.W.w[o * 68 + c] = p.ko1w[o * 72 + c]; }
  for (int k = tid; k < 512; k += 1024) { int o = k >> 3, c = k & 7; s.W.z[o * 8 + c] = p.ko1w[o * 72 + 64 + c]; }
  if (tid < 64) s.W.b[tid] = p.ko1b[tid];
  __syncthreads();

  // ---- ko1 ----
  if (tid < 256) {
    const int r = tid >> 4, ob = tid & 15;
    const float wrr = s.wsig[r][r];
    float z[8];
#pragma unroll
    for (int c = 0; c < 8; c++) z[c] = s.pi[r][c] + wrr * (s.act[r][c] - s.pi[r][c]);
#pragma unroll
    for (int oo = 0; oo < 4; oo++) {
      const int o = ob + 16 * oo;
      float a = s.W.b[o] + dot64(s.W.w + o * 68, &s.obs[r][0]);
#pragma unroll
      for (int c = 0; c < 8; c++) a += s.W.z[o * 8 + c] * z[c];
      s.ht[r][o] = lrelu(a);
    }
  }
  __syncthreads();
  stage68(s.W.w, p.ko2w, tid);
  if (tid < 64) s.W.b[tid] = p.ko2b[tid];
  __syncthreads();
  mini256(s.W.w, s.W.b, 1, s.ht, s.a2, 0, tid);   // key_o (overwrites query_z)
  __syncthreads();

  // ---- stage qo2^T ----
  for (int k = tid; k < 4096; k += 1024) { int o2 = k >> 6, o = k & 63; s.W.w[o * 68 + o2] = p.qo2w[k]; }
  if (tid < 64) s.W.b[tid] = p.qo2b[tid];
  __syncthreads();
  mini256(s.W.w, s.W.b, 0, s.a2, s.a1, 0, tid);   // ck (overwrites key_z)
  if (tid < 16) {
    float c = 0.f;
    for (int d = 0; d < 64; d++) c += s.a2[tid][d] * s.W.b[d];
    s.c0[tid] = c;
  }
  __syncthreads();

  // ---- stage qo1 (obs part + z part + bias) ----
  for (int k = tid; k < 4096; k += 1024) { int o = k >> 6, c = k & 63; s.W.w[o * 68 + c] = p.qo1w[o * 72 + c]; }
  for (int k = tid; k < 512; k += 1024) { int o = k >> 3, c = k & 7; s.wz8n[(o & 15) * 32 + (o >> 4) * 8 + c] = p.qo1w[o * 72 + 64 + c]; }
  if (tid < 64) s.W.b[tid] = p.qo1b[tid];
  __syncthreads();
  // Gqo -> GF2[t][j][g]
  if (tid < 256) {
    const int j = tid >> 4, ob = tid & 15;
#pragma unroll
    for (int oo = 0; oo < 4; oo++) {
      const int o = ob + 16 * oo;
      s.GF2[ob * 64 + j * 4 + oo] = dot64(s.W.w + o * 68, &s.obs[j][0]) + s.W.b[o];
    }
  }
  __syncthreads();

  // ---- qo-score (quad per (i,j) pair) ----
  {
    const int q = tid >> 2, g = tid & 3;
    const int qi = q >> 4, qj = q & 15;
    const float wij = s.wsig[qi][qj];
    float z[8];
#pragma unroll
    for (int c = 0; c < 8; c++) z[c] = s.pi[qj][c] + wij * (s.act[qj][c] - s.pi[qj][c]);
    float sc = 0.f;
#pragma unroll
    for (int t = 0; t < 16; t++) {
      const float4 wa = *(const float4*)(&s.wz8n[t * 32 + g * 8]);
      const float4 wb = *(const float4*)(&s.wz8n[t * 32 + g * 8 + 4]);
      float hv = s.GF2[t * 64 + qj * 4 + g]
        + wa.x * z[0] + wa.y * z[1] + wa.z * z[2] + wa.w * z[3]
        + wb.x * z[4] + wb.y * z[5] + wb.z * z[6] + wb.w * z[7];
      hv = lrelu(hv);
      sc += s.a1[qi][g * 16 + t] * hv;
    }
    sc += __shfl_xor(sc, 1);
    sc += __shfl_xor(sc, 2);
    if (g == 0) {
      float yv = (sc + s.c0[qi]) * 0.125f;
      yv = fminf(fmaxf(yv, -5.f), 5.f);
      ((float*)s.ht)[qi * 16 + qj] = __expf(yv);   // e
    }
  }
  __syncthreads();

  // ---- softmax of e ----
  if (tid < 256) {
    const int i = tid >> 4, j = tid & 15;
    const float* e = (const float*)s.ht;
    float m = -1e30f;
#pragma unroll
    for (int jj = 0; jj < 16; jj++) m = fmaxf(m, e[i * 16 + jj]);
    float den = 0.f;
#pragma unroll
    for (int jj = 0; jj < 16; jj++) den += __expf(e[i * 16 + jj] - m);
    const float val = __expf(e[i * 16 + j] - m) / den;
    s.wo[i][j] = val;
    p.wo[(size_t)b * 256 + tid] = val;
  }
  __syncthreads();

  // ---- out2 = wo[k][:] broadcast over i ----
  {
    const int q = tid >> 2, g = tid & 3, k = q & 15;
    *(float4*)(p.out2 + ((size_t)b * 256 + q) * 16 + 4 * g) =
        make_float4(s.wo[k][4 * g], s.wo[k][4 * g + 1], s.wo[k][4 * g + 2], s.wo[k][4 * g + 3]);
  }
}

// ======================= K2: f16 MFMA back half =======================

struct alignas(16) SMem2 {
  f16 obsH[16][72];        // obs rows, f16, frag-padded
  f16 AOsrcD[16 * 72];     // attn_src rows [k][o] (also wave1 H-scratch)
  f16 APT[64 * 24];        // AP^T [o][r]      (also wave0 H-scratch)
  f16 AextH[16 * 40];      // mixed A operand [k][32] (wo/16 | diag)
  f16 fv2pw[8 * 64];       // fv2 [v][o]
  f16 slice[8][1536];      // per-wave: H[16][72] -> AOT[64][24] -> mixedH[16][72] -> hiddenH[16][72]
  union {
    struct { f16 av1H[64 * 96]; f16 av2H[64 * 72]; } av;
    f16 fv1H[64 * 136];
  } W;
  float pi[16][8], act[16][8], wsig[16][16];
  float av1b[64], av2b[64], fv1b[64], fv2b[8];
};

__device__ __forceinline__ v8h bfrag(const f16* Wm, int stride, int nt, int ks, int lane) {
  const int n = lane & 15, q = lane >> 4;
  return *(const v8h*)(Wm + (nt * 16 + n) * stride + ks * 32 + q * 8);
}

// 2-layer av MLP for 16 rows: x_row(m) = [obsH[m] | z(m) | 0-pad]; acc2 = layer-2 output (no act)
__device__ __forceinline__ void av_mlp(const SMem2& s, f16* Hbuf, v8h az, int lane, v4f acc2[4]) {
  const int m = lane & 15, q = lane >> 4;
  const v8h a0 = *(const v8h*)(&s.obsH[m][q * 8]);
  const v8h a1 = *(const v8h*)(&s.obsH[m][32 + q * 8]);
#pragma unroll
  for (int nt = 0; nt < 4; nt++) {
    const float bv = s.av1b[nt * 16 + m];
    v4f acc = {bv, bv, bv, bv};
    acc = __builtin_amdgcn_mfma_f32_16x16x32_f16(a0, bfrag(s.W.av.av1H, 96, nt, 0, lane), acc, 0, 0, 0);
    acc = __builtin_amdgcn_mfma_f32_16x16x32_f16(a1, bfrag(s.W.av.av1H, 96, nt, 1, lane), acc, 0, 0, 0);
    acc = __builtin_amdgcn_mfma_f32_16x16x32_f16(az, bfrag(s.W.av.av1H, 96, nt, 2, lane), acc, 0, 0, 0);
#pragma unroll
    for (int reg = 0; reg < 4; reg++)
      Hbuf[(q * 4 + reg) * 72 + nt * 16 + m] = (f16)lrelu(acc[reg]);
  }
  const v8h h0 = *(const v8h*)(Hbuf + m * 72 + q * 8);
  const v8h h1 = *(const v8h*)(Hbuf + m * 72 + 32 + q * 8);
#pragma unroll
  for (int nt = 0; nt < 4; nt++) {
    const float bv = s.av2b[nt * 16 + m];
    v4f acc = {bv, bv, bv, bv};
    acc = __builtin_amdgcn_mfma_f32_16x16x32_f16(h0, bfrag(s.W.av.av2H, 72, nt, 0, lane), acc, 0, 0, 0);
    acc = __builtin_amdgcn_mfma_f32_16x16x32_f16(h1, bfrag(s.W.av.av2H, 72, nt, 1, lane), acc, 0, 0, 0);
    acc2[nt] = acc;
  }
}

__global__ __launch_bounds__(512) void critic_k2(P p) {
  __shared__ SMem2 s;
  const int tid = threadIdx.x;
  const int b = blockIdx.x >> 1, ibase = (blockIdx.x & 1) * 8;
  const int w = tid >> 6, lane = tid & 63;
  const int m = lane & 15, quad = lane >> 4;
  const int i = ibase + w;

  // ---- phase 1: stage everything except fv1 ----
  for (int k = tid; k < 1024; k += 512) s.obsH[k >> 6][k & 63] = (f16)p.obs[(size_t)b * 1024 + k];
  if (tid < 128) { s.pi[tid >> 3][tid & 7] = p.pol[(size_t)b * 128 + tid]; }
  else if (tid < 256) { int k = tid - 128; s.act[k >> 3][k & 7] = p.act[(size_t)b * 128 + k]; }
  for (int k = tid; k < 256; k += 512) s.wsig[k >> 4][k & 15] = p.wsig[(size_t)b * 256 + k];
  {
    const int kk = tid >> 5, j2 = tid & 31;   // tid<512 covers 16x32
    float v = 0.f;
    if (j2 < 16) v = p.wo[(size_t)b * 256 + kk * 16 + j2] * 0.0625f;
    else if (j2 - 16 == kk) v = p.wo[(size_t)b * 256 + kk * 16 + kk] * 0.0625f;
    s.AextH[kk * 40 + j2] = (f16)v;
  }
  for (int k = tid; k < 4608; k += 512) { int r = k / 72, c = k - r * 72; s.W.av.av1H[r * 96 + c] = (f16)p.av1w[k]; }
  for (int k = tid; k < 64 * 24; k += 512) { int r = k / 24, c = 72 + (k - r * 24); s.W.av.av1H[r * 96 + c] = (f16)0.f; }
  for (int k = tid; k < 4096; k += 512) s.W.av.av2H[(k >> 6) * 72 + (k & 63)] = (f16)p.av2w[k];
  for (int k = tid; k < 512; k += 512) s.fv2pw[k] = (f16)p.fv2w[k];
  if (tid < 64) { s.av1b[tid] = p.av1b[tid]; s.av2b[tid] = p.av2b[tid]; s.fv1b[tid] = p.fv1b[tid]; }
  else if (tid < 72) s.fv2b[tid - 64] = p.fv2b[tid - 64];
  __syncthreads();

  // ---- AO_i per wave ----
  f16* Sl = &s.slice[w][0];
  {
    v8h az = {};
    if (quad == 0) {
      const float wv = s.wsig[i][m];
#pragma unroll
      for (int c = 0; c < 8; c++) az[c] = (f16)(s.pi[m][c] + wv * (s.act[m][c] - s.pi[m][c]));
    }
    v4f acc2[4];
    av_mlp(s, Sl, az, lane, acc2);
    // AOT[o][j]
#pragma unroll
    for (int nt = 0; nt < 4; nt++)
#pragma unroll
      for (int reg = 0; reg < 4; reg++)
        Sl[(nt * 16 + m) * 24 + quad * 4 + reg] = (f16)acc2[nt][reg];
  }
  if (w == 0) {  // AP rows (x = [obs | pi])
    v8h az = {};
    if (quad == 0) {
#pragma unroll
      for (int c = 0; c < 8; c++) az[c] = (f16)s.pi[m][c];
    }
    v4f acc2[4];
    av_mlp(s, s.APT, az, lane, acc2);
#pragma unroll
    for (int nt = 0; nt < 4; nt++)
#pragma unroll
      for (int reg = 0; reg < 4; reg++)
        s.APT[(nt * 16 + m) * 24 + quad * 4 + reg] = (f16)acc2[nt][reg];
  }
  if (w == 1) {  // attn_src rows (x = [obs_k | z_kk]) -> AOsrcD[k][o]
    v8h az = {};
    if (quad == 0) {
      const float wv = s.wsig[m][m];
#pragma unroll
      for (int c = 0; c < 8; c++) az[c] = (f16)(s.pi[m][c] + wv * (s.act[m][c] - s.pi[m][c]));
    }
    v4f acc2[4];
    av_mlp(s, s.AOsrcD, az, lane, acc2);
#pragma unroll
    for (int nt = 0; nt < 4; nt++)
#pragma unroll
      for (int reg = 0; reg < 4; reg++)
        s.AOsrcD[(quad * 4 + reg) * 72 + nt * 16 + m] = (f16)acc2[nt][reg];
  }
  __syncthreads();

  // ---- stage fv1 over av weights ----
  for (int k = tid; k < 8192; k += 512) s.W.fv1H[(k >> 7) * 136 + (k & 127)] = (f16)p.fv1w[k];
  __syncthreads();

  // ---- mixed (per wave): D[k][o] = Aext[16x32] x Bext[32x64] ----
  {
    const v8h am = *(const v8h*)(&s.AextH[m * 40 + quad * 8]);
    v4f macc[4];
#pragma unroll
    for (int nt = 0; nt < 4; nt++) {
      const int o = nt * 16 + m;
      v8h bf;
      if (quad < 2) {
        bf = *(const v8h*)(Sl + o * 24 + quad * 8);
      } else {
        const v8h apv = *(const v8h*)(&s.APT[o * 24 + (quad - 2) * 8]);
        const v8h aov = *(const v8h*)(Sl + o * 24 + (quad - 2) * 8);
        bf = apv - aov;
      }
      v4f z4 = {0.f, 0.f, 0.f, 0.f};
      macc[nt] = __builtin_amdgcn_mfma_f32_16x16x32_f16(am, bf, z4, 0, 0, 0);
    }
    // mixedH[k][o] (overwrites AOT after all reads)
#pragma unroll
    for (int nt = 0; nt < 4; nt++)
#pragma unroll
      for (int reg = 0; reg < 4; reg++)
        Sl[(quad * 4 + reg) * 72 + nt * 16 + m] = (f16)macc[nt][reg];
  }

  // ---- fv1 (per wave): x[k] = [AOsrc[k] | mixed_i[k]] ----
  {
    const v8h f0 = *(const v8h*)(&s.AOsrcD[m * 72 + quad * 8]);
    const v8h f1 = *(const v8h*)(&s.AOsrcD[m * 72 + 32 + quad * 8]);
    const v8h f2 = *(const v8h*)(Sl + m * 72 + quad * 8);
    const v8h f3 = *(const v8h*)(Sl + m * 72 + 32 + quad * 8);
#pragma unroll
    for (int nt = 0; nt < 4; nt++) {
      const float bv = s.fv1b[nt * 16 + m];
      v4f acc = {bv, bv, bv, bv};
      acc = __builtin_amdgcn_mfma_f32_16x16x32_f16(f0, bfrag(s.W.fv1H, 136, nt, 0, lane), acc, 0, 0, 0);
      acc = __builtin_amdgcn_mfma_f32_16x16x32_f16(f1, bfrag(s.W.fv1H, 136, nt, 1, lane), acc, 0, 0, 0);
      acc = __builtin_amdgcn_mfma_f32_16x16x32_f16(f2, bfrag(s.W.fv1H, 136, nt, 2, lane), acc, 0, 0, 0);
      acc = __builtin_amdgcn_mfma_f32_16x16x32_f16(f3, bfrag(s.W.fv1H, 136, nt, 3, lane), acc, 0, 0, 0);
#pragma unroll
      for (int reg = 0; reg < 4; reg++)
        Sl[(quad * 4 + reg) * 72 + nt * 16 + m] = (f16)lrelu(acc[reg]);   // hiddenH
    }
  }
  // ---- fv2: lane (k=m, v-pair=quad) ----
  {
    const int g2 = quad;
    float y0 = s.fv2b[2 * g2], y1 = s.fv2b[2 * g2 + 1];
#pragma unroll
    for (int o2 = 0; o2 < 32; o2++) {
      const h2 hh = *(const h2*)(Sl + m * 72 + 2 * o2);
      const h2 w0 = *(const h2*)(&s.fv2pw[(2 * g2) * 64 + 2 * o2]);
      const h2 w1 = *(const h2*)(&s.fv2pw[(2 * g2 + 1) * 64 + 2 * o2]);
      y0 = fdot2f(w0, hh, y0);
      y1 = fdot2f(w1, hh, y1);
    }
    *(float2*)(p.out0 + ((size_t)b * 256 + i * 16 + m) * 8 + 2 * g2) = make_float2(y0, y1);
  }
}

extern "C" void kernel_launch(void* const* d_in, const int* in_sizes, int n_in,
                              void* d_out, int out_size, void* d_ws, size_t ws_size,
                              hipStream_t stream) {
  P p;
  p.obs = (const float*)d_in[0];
  p.pol = (const float*)d_in[1];
  p.act = (const float*)d_in[2];
  p.kw1w = (const float*)d_in[3];  p.kw1b = (const float*)d_in[4];
  p.kw2w = (const float*)d_in[5];  p.kw2b = (const float*)d_in[6];
  p.qw1w = (const float*)d_in[7];  p.qw1b = (const float*)d_in[8];
  p.qw2w = (const float*)d_in[9];  p.qw2b = (const float*)d_in[10];
  p.ko1w = (const float*)d_in[11]; p.ko1b = (const float*)d_in[12];
  p.ko2w = (const float*)d_in[13]; p.ko2b = (const float*)d_in[14];
  p.qo1w = (const float*)d_in[15]; p.qo1b = (const float*)d_in[16];
  p.qo2w = (const float*)d_in[17]; p.qo2b = (const float*)d_in[18];
  p.av1w = (const float*)d_in[19]; p.av1b = (const float*)d_in[20];
  p.av2w = (const float*)d_in[21]; p.av2b = (const float*)d_in[22];
  p.fv1w = (const float*)d_in[23]; p.fv1b = (const float*)d_in[24];
  p.fv2w = (const float*)d_in[25]; p.fv2b = (const float*)d_in[26];

  const int Bn = in_sizes[0] / (A_ * DOBS_);   // 128
  p.out0 = (float*)d_out;
  p.out1 = p.out0 + (size_t)Bn * A_ * A_ * NA_;
  p.out2 = p.out1 + (size_t)Bn * A_ * A_;
  p.wsig = (float*)d_ws;
  p.wo = p.wsig + (size_t)Bn * 256;

  hipLaunchKernelGGL(critic_k1, dim3(Bn), dim3(1024), 0, stream, p);
  hipLaunchKernelGGL(critic_k2, dim3(2 * Bn), dim3(512), 0, stream, p);
}

// Round 4
// 134.780 us; speedup vs baseline: 1.6876x; 1.0736x over previous
//
#include <hip/hip_runtime.h>

#define A_ 16
#define NA_ 8
#define DOBS_ 64

typedef _Float16 f16;
typedef f16 h2 __attribute__((ext_vector_type(2)));
typedef f16 v8h __attribute__((ext_vector_type(8)));
typedef float v4f __attribute__((ext_vector_type(4)));

__device__ __forceinline__ float fdot2f(h2 a, h2 b, float c) {
  return __builtin_amdgcn_fdot2(a, b, c, false);
}
__device__ __forceinline__ float lrelu(float x) { return x > 0.f ? x : 0.01f * x; }

struct P {
  const float *obs, *pol, *act;
  const float *kw1w, *kw1b, *kw2w, *kw2b, *qw1w, *qw1b, *qw2w, *qw2b;
  const float *ko1w, *ko1b, *ko2w, *ko2b, *qo1w, *qo1b, *qo2w, *qo2b;
  const float *av1w, *av1b, *av2w, *av2b, *fv1w, *fv1b, *fv2w, *fv2b;
  float *out0, *out1, *out2;
  float *wsig, *wo;   // workspace
};

// ======================= K1: fp32 front (register-prefetched weights) =======================

#define SM_WQ0 0
#define SM_WQ1 4096
#define SM_S0 8192
#define SM_S1 9280
#define SM_S2 10368
#define SM_S3 11456
#define SM_OBS 12544
#define SM_GF2 13632
#define SM_WZ8 14656
#define SM_WSIG 15168
#define SM_WO 15424
#define SM_PI 15680
#define SM_ACT 15808
#define SM_C0 15936
#define SM_TOT 15952   // 63808 B

// Wq layout: float4 chunk (d4, o) at float4-index d4*64+o. Thread's out = o = tid&63:
// reads ((float4*)Wq)[d4*64+o] are lane-consecutive (conflict-free); x reads broadcast.
__device__ __forceinline__ float dotWq(const float* Wq, const float* xrow, int o) {
  float a0 = 0.f, a1 = 0.f, a2 = 0.f, a3 = 0.f;
#pragma unroll
  for (int d4 = 0; d4 < 16; d4++) {
    const float4 w = ((const float4*)Wq)[d4 * 64 + o];
    const float4 x = *(const float4*)(xrow + 4 * d4);
    a0 += w.x * x.x; a1 += w.y * x.y; a2 += w.z * x.z; a3 += w.w * x.w;
  }
  return (a0 + a1) + (a2 + a3);
}

__global__ __launch_bounds__(1024) void critic_k1(P p) {
  __shared__ float sm[SM_TOT];
  const int tid = threadIdx.x;
  const int b = blockIdx.x;
  const int o = tid & 63, r = tid >> 6;

  // ---- register prefetch: thread holds W-chunk (row o, d-quad r) for each matrix ----
  const float4 Rkw1 = *(const float4*)(p.kw1w + o * 64 + 4 * r);
  const float4 Rqw1 = *(const float4*)(p.qw1w + o * 64 + 4 * r);
  const float4 Rkw2 = *(const float4*)(p.kw2w + o * 64 + 4 * r);
  const float4 Rqw2 = *(const float4*)(p.qw2w + o * 64 + 4 * r);
  const float4 Rko2 = *(const float4*)(p.ko2w + o * 64 + 4 * r);
  const float4 Rko1 = *(const float4*)(p.ko1w + o * 72 + 4 * r);
  const float4 Rqo1 = *(const float4*)(p.qo1w + o * 72 + 4 * r);
  const float4 Rkz0 = *(const float4*)(p.ko1w + o * 72 + 64);
  const float4 Rkz1 = *(const float4*)(p.ko1w + o * 72 + 68);
  float4 Rqo2;   // transposed chunk: M[o][4r..4r+3] = qo2w[4r+c][o]
  Rqo2.x = p.qo2w[(4 * r + 0) * 64 + o];
  Rqo2.y = p.qo2w[(4 * r + 1) * 64 + o];
  Rqo2.z = p.qo2w[(4 * r + 2) * 64 + o];
  Rqo2.w = p.qo2w[(4 * r + 3) * 64 + o];
  const float Bkw1 = p.kw1b[o], Bkw2 = p.kw2b[o], Bqw1 = p.qw1b[o], Bqw2 = p.qw2b[o];
  const float Bko1 = p.ko1b[o], Bko2 = p.ko2b[o], Bqo1 = p.qo1b[o], Bqo2v = p.qo2b[o];

  // ---- inputs + wz8n + phase-A weights ----
  sm[SM_OBS + r * 68 + o] = p.obs[(size_t)b * 1024 + tid];
  if (tid < 128) sm[SM_PI + tid] = p.pol[(size_t)b * 128 + tid];
  else if (tid < 256) sm[SM_ACT + tid - 128] = p.act[(size_t)b * 128 + tid - 128];
  if (tid < 512) {
    const int oo = tid >> 3, c = tid & 7;
    sm[SM_WZ8 + (oo & 15) * 32 + (oo >> 4) * 8 + c] = p.qo1w[oo * 72 + 64 + c];
  }
  ((float4*)(sm + SM_WQ0))[tid] = Rkw1;
  ((float4*)(sm + SM_WQ1))[tid] = Rqw1;
  __syncthreads();

  // ---- A: kw1 hidden (s0), qw1 hidden (s1) ----
  {
    const float* xr = sm + SM_OBS + r * 68;
    sm[SM_S0 + r * 68 + o] = lrelu(dotWq(sm + SM_WQ0, xr, o) + Bkw1);
    sm[SM_S1 + r * 68 + o] = lrelu(dotWq(sm + SM_WQ1, xr, o) + Bqw1);
  }
  __syncthreads();
  ((float4*)(sm + SM_WQ0))[tid] = Rkw2;
  ((float4*)(sm + SM_WQ1))[tid] = Rqw2;
  __syncthreads();

  // ---- B: key_z (s2), query_z (s3) ----
  sm[SM_S2 + r * 68 + o] = dotWq(sm + SM_WQ0, sm + SM_S0 + r * 68, o) + Bkw2;
  sm[SM_S3 + r * 68 + o] = dotWq(sm + SM_WQ1, sm + SM_S1 + r * 68, o) + Bqw2;
  __syncthreads();
  ((float4*)(sm + SM_WQ0))[tid] = Rqo1;   // qo1 obs-part (C)
  ((float4*)(sm + SM_WQ1))[tid] = Rko1;   // ko1 obs-part (D)
  __syncthreads();

  // ---- C: Gqo + score/sigmoid ----
  {
    const float gv = dotWq(sm + SM_WQ0, sm + SM_OBS + r * 68, o) + Bqo1;
    sm[SM_GF2 + (o & 15) * 64 + r * 4 + (o >> 4)] = gv;   // GF2[t][j=r][g]
    const int j = (tid >> 2) & 15, g = tid & 3;
    float a0 = 0.f, a1 = 0.f, a2 = 0.f, a3 = 0.f;
#pragma unroll
    for (int t4 = 0; t4 < 4; t4++) {
      const float4 qv = *(const float4*)(sm + SM_S3 + r * 68 + g * 16 + 4 * t4);
      const float4 kv = *(const float4*)(sm + SM_S2 + j * 68 + g * 16 + 4 * t4);
      a0 += qv.x * kv.x; a1 += qv.y * kv.y; a2 += qv.z * kv.z; a3 += qv.w * kv.w;
    }
    float sc = (a0 + a1) + (a2 + a3);
    sc += __shfl_xor(sc, 1);
    sc += __shfl_xor(sc, 2);
    if (g == 0) {
      const float w = 1.f / (1.f + __expf(-sc * 0.125f));
      sm[SM_WSIG + r * 16 + j] = w;
      p.out1[(size_t)b * 256 + r * 16 + j] = w;
      p.wsig[(size_t)b * 256 + r * 16 + j] = w;
    }
  }
  __syncthreads();

  // ---- D: ko1 hidden (s0); stage ko2 ----
  {
    float acc = dotWq(sm + SM_WQ1, sm + SM_OBS + r * 68, o) + Bko1;
    const float wrr = sm[SM_WSIG + r * 16 + r];
    const float* piR = sm + SM_PI + r * 8;
    const float* acR = sm + SM_ACT + r * 8;
    float z[8];
#pragma unroll
    for (int c = 0; c < 8; c++) z[c] = piR[c] + wrr * (acR[c] - piR[c]);
    acc += Rkz0.x * z[0] + Rkz0.y * z[1] + Rkz0.z * z[2] + Rkz0.w * z[3]
         + Rkz1.x * z[4] + Rkz1.y * z[5] + Rkz1.z * z[6] + Rkz1.w * z[7];
    sm[SM_S0 + r * 68 + o] = lrelu(acc);
    ((float4*)(sm + SM_WQ0))[tid] = Rko2;   // Wq0 free after C
  }
  __syncthreads();

  // ---- E: key_o (s1); stage qo2T ----
  sm[SM_S1 + r * 68 + o] = dotWq(sm + SM_WQ0, sm + SM_S0 + r * 68, o) + Bko2;
  ((float4*)(sm + SM_WQ1))[tid] = Rqo2;     // Wq1 free after D
  __syncthreads();

  // ---- F: ck (s2) + c0 ----
  {
    sm[SM_S2 + r * 68 + o] = dotWq(sm + SM_WQ1, sm + SM_S1 + r * 68, o);
    float t = sm[SM_S1 + r * 68 + o] * Bqo2v;
#pragma unroll
    for (int mm = 1; mm < 64; mm <<= 1) t += __shfl_xor(t, mm);
    if (o == 0) sm[SM_C0 + r] = t;
  }
  __syncthreads();

  // ---- G: qo-score -> e (s3 flat) ----
  {
    const int j = (tid >> 2) & 15, g = tid & 3;
    const float wij = sm[SM_WSIG + r * 16 + j];
    const float* piR = sm + SM_PI + j * 8;
    const float* acR = sm + SM_ACT + j * 8;
    float z[8];
#pragma unroll
    for (int c = 0; c < 8; c++) z[c] = piR[c] + wij * (acR[c] - piR[c]);
    float sc = 0.f;
#pragma unroll
    for (int t = 0; t < 16; t++) {
      const float4 wa = *(const float4*)(sm + SM_WZ8 + t * 32 + g * 8);
      const float4 wb = *(const float4*)(sm + SM_WZ8 + t * 32 + g * 8 + 4);
      float hv = sm[SM_GF2 + t * 64 + j * 4 + g]
        + wa.x * z[0] + wa.y * z[1] + wa.z * z[2] + wa.w * z[3]
        + wb.x * z[4] + wb.y * z[5] + wb.z * z[6] + wb.w * z[7];
      hv = lrelu(hv);
      sc += sm[SM_S2 + r * 68 + g * 16 + t] * hv;
    }
    sc += __shfl_xor(sc, 1);
    sc += __shfl_xor(sc, 2);
    if (g == 0) {
      float yv = (sc + sm[SM_C0 + r]) * 0.125f;
      yv = fminf(fmaxf(yv, -5.f), 5.f);
      sm[SM_S3 + r * 16 + j] = __expf(yv);
    }
  }
  __syncthreads();

  // ---- H: softmax + outputs ----
  if (tid < 256) {
    const int i = tid >> 4, j = tid & 15;
    const float* e = sm + SM_S3;
    float m = -1e30f;
#pragma unroll
    for (int jj = 0; jj < 16; jj++) m = fmaxf(m, e[i * 16 + jj]);
    float den = 0.f;
#pragma unroll
    for (int jj = 0; jj < 16; jj++) den += __expf(e[i * 16 + jj] - m);
    const float val = __expf(e[i * 16 + j] - m) / den;
    sm[SM_WO + i * 16 + j] = val;
    p.wo[(size_t)b * 256 + tid] = val;
  }
  __syncthreads();
  {
    const int q = tid >> 2, g = tid & 3, k = q & 15;
    *(float4*)(p.out2 + ((size_t)b * 256 + q) * 16 + 4 * g) =
        *(const float4*)(sm + SM_WO + k * 16 + 4 * g);
  }
}

// ======================= K2: f16 MFMA back half =======================

struct alignas(16) SMem2 {
  f16 obsH[16][72];
  f16 AOsrcD[16 * 72];
  f16 APT[64 * 24];
  f16 AextH[16 * 40];
  f16 fv2pw[8 * 64];
  f16 slice[8][1536];
  union {
    struct { f16 av1H[64 * 96]; f16 av2H[64 * 72]; } av;
    f16 fv1H[64 * 136];
  } W;
  float pi[16][8], act[16][8], wsig[16][16];
  float av1b[64], av2b[64], fv1b[64], fv2b[8];
};

__device__ __forceinline__ v8h bfrag(const f16* Wm, int stride, int nt, int ks, int lane) {
  const int n = lane & 15, q = lane >> 4;
  return *(const v8h*)(Wm + (nt * 16 + n) * stride + ks * 32 + q * 8);
}

__device__ __forceinline__ void av_mlp(const SMem2& s, f16* Hbuf, v8h az, int lane, v4f acc2[4]) {
  const int m = lane & 15, q = lane >> 4;
  const v8h a0 = *(const v8h*)(&s.obsH[m][q * 8]);
  const v8h a1 = *(const v8h*)(&s.obsH[m][32 + q * 8]);
#pragma unroll
  for (int nt = 0; nt < 4; nt++) {
    const float bv = s.av1b[nt * 16 + m];
    v4f acc = {bv, bv, bv, bv};
    acc = __builtin_amdgcn_mfma_f32_16x16x32_f16(a0, bfrag(s.W.av.av1H, 96, nt, 0, lane), acc, 0, 0, 0);
    acc = __builtin_amdgcn_mfma_f32_16x16x32_f16(a1, bfrag(s.W.av.av1H, 96, nt, 1, lane), acc, 0, 0, 0);
    acc = __builtin_amdgcn_mfma_f32_16x16x32_f16(az, bfrag(s.W.av.av1H, 96, nt, 2, lane), acc, 0, 0, 0);
#pragma unroll
    for (int reg = 0; reg < 4; reg++)
      Hbuf[(q * 4 + reg) * 72 + nt * 16 + m] = (f16)lrelu(acc[reg]);
  }
  const v8h h0 = *(const v8h*)(Hbuf + m * 72 + q * 8);
  const v8h h1 = *(const v8h*)(Hbuf + m * 72 + 32 + q * 8);
#pragma unroll
  for (int nt = 0; nt < 4; nt++) {
    const float bv = s.av2b[nt * 16 + m];
    v4f acc = {bv, bv, bv, bv};
    acc = __builtin_amdgcn_mfma_f32_16x16x32_f16(h0, bfrag(s.W.av.av2H, 72, nt, 0, lane), acc, 0, 0, 0);
    acc = __builtin_amdgcn_mfma_f32_16x16x32_f16(h1, bfrag(s.W.av.av2H, 72, nt, 1, lane), acc, 0, 0, 0);
    acc2[nt] = acc;
  }
}

__global__ __launch_bounds__(512) void critic_k2(P p) {
  __shared__ SMem2 s;
  const int tid = threadIdx.x;
  const int b = blockIdx.x >> 1, ibase = (blockIdx.x & 1) * 8;
  const int w = tid >> 6, lane = tid & 63;
  const int m = lane & 15, quad = lane >> 4;
  const int i = ibase + w;

  // fv1 prefetched to registers (written to LDS after av phase, no mid-kernel global wait)
  float4 rfv[4];
#pragma unroll
  for (int qq = 0; qq < 4; qq++) rfv[qq] = ((const float4*)p.fv1w)[tid * 4 + qq];

  // ---- stage inputs + av weights ----
  for (int k = tid; k < 1024; k += 512) s.obsH[k >> 6][k & 63] = (f16)p.obs[(size_t)b * 1024 + k];
  if (tid < 128) { s.pi[tid >> 3][tid & 7] = p.pol[(size_t)b * 128 + tid]; }
  else if (tid < 256) { int k = tid - 128; s.act[k >> 3][k & 7] = p.act[(size_t)b * 128 + k]; }
  for (int k = tid; k < 256; k += 512) s.wsig[k >> 4][k & 15] = p.wsig[(size_t)b * 256 + k];
  {
    const int kk = tid >> 5, j2 = tid & 31;
    float v = 0.f;
    if (j2 < 16) v = p.wo[(size_t)b * 256 + kk * 16 + j2] * 0.0625f;
    else if (j2 - 16 == kk) v = p.wo[(size_t)b * 256 + kk * 16 + kk] * 0.0625f;
    s.AextH[kk * 40 + j2] = (f16)v;
  }
  {
    const int row = tid >> 3, c0 = (tid & 7) * 9;
#pragma unroll
    for (int c = 0; c < 9; c++) s.W.av.av1H[row * 96 + c0 + c] = (f16)p.av1w[row * 72 + c0 + c];
  }
  {
    const int row = tid >> 3, c0 = 72 + (tid & 7) * 3;
#pragma unroll
    for (int c = 0; c < 3; c++) s.W.av.av1H[row * 96 + c0 + c] = (f16)0.f;
  }
  for (int k = tid; k < 4096; k += 512) s.W.av.av2H[(k >> 6) * 72 + (k & 63)] = (f16)p.av2w[k];
  s.fv2pw[tid] = (f16)p.fv2w[tid];
  if (tid < 64) { s.av1b[tid] = p.av1b[tid]; s.av2b[tid] = p.av2b[tid]; s.fv1b[tid] = p.fv1b[tid]; }
  else if (tid < 72) s.fv2b[tid - 64] = p.fv2b[tid - 64];
  __syncthreads();

  // ---- AO_i per wave ----
  f16* Sl = &s.slice[w][0];
  {
    v8h az = {};
    if (quad == 0) {
      const float wv = s.wsig[i][m];
#pragma unroll
      for (int c = 0; c < 8; c++) az[c] = (f16)(s.pi[m][c] + wv * (s.act[m][c] - s.pi[m][c]));
    }
    v4f acc2[4];
    av_mlp(s, Sl, az, lane, acc2);
#pragma unroll
    for (int nt = 0; nt < 4; nt++)
#pragma unroll
      for (int reg = 0; reg < 4; reg++)
        Sl[(nt * 16 + m) * 24 + quad * 4 + reg] = (f16)acc2[nt][reg];
  }
  if (w == 0) {  // AP rows
    v8h az = {};
    if (quad == 0) {
#pragma unroll
      for (int c = 0; c < 8; c++) az[c] = (f16)s.pi[m][c];
    }
    v4f acc2[4];
    av_mlp(s, s.APT, az, lane, acc2);
#pragma unroll
    for (int nt = 0; nt < 4; nt++)
#pragma unroll
      for (int reg = 0; reg < 4; reg++)
        s.APT[(nt * 16 + m) * 24 + quad * 4 + reg] = (f16)acc2[nt][reg];
  }
  if (w == 1) {  // attn_src rows
    v8h az = {};
    if (quad == 0) {
      const float wv = s.wsig[m][m];
#pragma unroll
      for (int c = 0; c < 8; c++) az[c] = (f16)(s.pi[m][c] + wv * (s.act[m][c] - s.pi[m][c]));
    }
    v4f acc2[4];
    av_mlp(s, s.AOsrcD, az, lane, acc2);
#pragma unroll
    for (int nt = 0; nt < 4; nt++)
#pragma unroll
      for (int reg = 0; reg < 4; reg++)
        s.AOsrcD[(quad * 4 + reg) * 72 + nt * 16 + m] = (f16)acc2[nt][reg];
  }
  __syncthreads();

  // ---- write fv1 from registers (no global wait) ----
#pragma unroll
  for (int qq = 0; qq < 4; qq++) {
    const int e0 = tid * 16 + qq * 4;
    h2* d = (h2*)&s.W.fv1H[(e0 >> 7) * 136 + (e0 & 127)];
    d[0] = h2{(f16)rfv[qq].x, (f16)rfv[qq].y};
    d[1] = h2{(f16)rfv[qq].z, (f16)rfv[qq].w};
  }
  __syncthreads();

  // ---- mixed ----
  {
    const v8h am = *(const v8h*)(&s.AextH[m * 40 + quad * 8]);
    v4f macc[4];
#pragma unroll
    for (int nt = 0; nt < 4; nt++) {
      const int o = nt * 16 + m;
      v8h bf;
      if (quad < 2) {
        bf = *(const v8h*)(Sl + o * 24 + quad * 8);
      } else {
        const v8h apv = *(const v8h*)(&s.APT[o * 24 + (quad - 2) * 8]);
        const v8h aov = *(const v8h*)(Sl + o * 24 + (quad - 2) * 8);
        bf = apv - aov;
      }
      v4f z4 = {0.f, 0.f, 0.f, 0.f};
      macc[nt] = __builtin_amdgcn_mfma_f32_16x16x32_f16(am, bf, z4, 0, 0, 0);
    }
#pragma unroll
    for (int nt = 0; nt < 4; nt++)
#pragma unroll
      for (int reg = 0; reg < 4; reg++)
        Sl[(quad * 4 + reg) * 72 + nt * 16 + m] = (f16)macc[nt][reg];
  }

  // ---- fv1 ----
  {
    const v8h f0 = *(const v8h*)(&s.AOsrcD[m * 72 + quad * 8]);
    const v8h f1 = *(const v8h*)(&s.AOsrcD[m * 72 + 32 + quad * 8]);
    const v8h f2 = *(const v8h*)(Sl + m * 72 + quad * 8);
    const v8h f3 = *(const v8h*)(Sl + m * 72 + 32 + quad * 8);
#pragma unroll
    for (int nt = 0; nt < 4; nt++) {
      const float bv = s.fv1b[nt * 16 + m];
      v4f acc = {bv, bv, bv, bv};
      acc = __builtin_amdgcn_mfma_f32_16x16x32_f16(f0, bfrag(s.W.fv1H, 136, nt, 0, lane), acc, 0, 0, 0);
      acc = __builtin_amdgcn_mfma_f32_16x16x32_f16(f1, bfrag(s.W.fv1H, 136, nt, 1, lane), acc, 0, 0, 0);
      acc = __builtin_amdgcn_mfma_f32_16x16x32_f16(f2, bfrag(s.W.fv1H, 136, nt, 2, lane), acc, 0, 0, 0);
      acc = __builtin_amdgcn_mfma_f32_16x16x32_f16(f3, bfrag(s.W.fv1H, 136, nt, 3, lane), acc, 0, 0, 0);
#pragma unroll
      for (int reg = 0; reg < 4; reg++)
        Sl[(quad * 4 + reg) * 72 + nt * 16 + m] = (f16)lrelu(acc[reg]);
    }
  }
  // ---- fv2 ----
  {
    const int g2 = quad;
    float y0 = s.fv2b[2 * g2], y1 = s.fv2b[2 * g2 + 1];
#pragma unroll
    for (int o2 = 0; o2 < 32; o2++) {
      const h2 hh = *(const h2*)(Sl + m * 72 + 2 * o2);
      const h2 w0 = *(const h2*)(&s.fv2pw[(2 * g2) * 64 + 2 * o2]);
      const h2 w1 = *(const h2*)(&s.fv2pw[(2 * g2 + 1) * 64 + 2 * o2]);
      y0 = fdot2f(w0, hh, y0);
      y1 = fdot2f(w1, hh, y1);
    }
    *(float2*)(p.out0 + ((size_t)b * 256 + i * 16 + m) * 8 + 2 * g2) = make_float2(y0, y1);
  }
}

extern "C" void kernel_launch(void* const* d_in, const int* in_sizes, int n_in,
                              void* d_out, int out_size, void* d_ws, size_t ws_size,
                              hipStream_t stream) {
  P p;
  p.obs = (const float*)d_in[0];
  p.pol = (const float*)d_in[1];
  p.act = (const float*)d_in[2];
  p.kw1w = (const float*)d_in[3];  p.kw1b = (const float*)d_in[4];
  p.kw2w = (const float*)d_in[5];  p.kw2b = (const float*)d_in[6];
  p.qw1w = (const float*)d_in[7];  p.qw1b = (const float*)d_in[8];
  p.qw2w = (const float*)d_in[9];  p.qw2b = (const float*)d_in[10];
  p.ko1w = (const float*)d_in[11]; p.ko1b = (const float*)d_in[12];
  p.ko2w = (const float*)d_in[13]; p.ko2b = (const float*)d_in[14];
  p.qo1w = (const float*)d_in[15]; p.qo1b = (const float*)d_in[16];
  p.qo2w = (const float*)d_in[17]; p.qo2b = (const float*)d_in[18];
  p.av1w = (const float*)d_in[19]; p.av1b = (const float*)d_in[20];
  p.av2w = (const float*)d_in[21]; p.av2b = (const float*)d_in[22];
  p.fv1w = (const float*)d_in[23]; p.fv1b = (const float*)d_in[24];
  p.fv2w = (const float*)d_in[25]; p.fv2b = (const float*)d_in[26];

  const int Bn = in_sizes[0] / (A_ * DOBS_);   // 128
  p.out0 = (float*)d_out;
  p.out1 = p.out0 + (size_t)Bn * A_ * A_ * NA_;
  p.out2 = p.out1 + (size_t)Bn * A_ * A_;
  p.wsig = (float*)d_ws;
  p.wo = p.wsig + (size_t)Bn * 256;

  hipLaunchKernelGGL(critic_k1, dim3(Bn), dim3(1024), 0, stream, p);
  hipLaunchKernelGGL(critic_k2, dim3(2 * Bn), dim3(512), 0, stream, p);
}

// Round 5
// 130.415 us; speedup vs baseline: 1.7441x; 1.0335x over previous
//
#include <hip/hip_runtime.h>

#define A_ 16
#define NA_ 8
#define DOBS_ 64

typedef _Float16 f16;
typedef f16 h2 __attribute__((ext_vector_type(2)));
typedef f16 v8h __attribute__((ext_vector_type(8)));
typedef float v4f __attribute__((ext_vector_type(4)));

__device__ __forceinline__ float fdot2f(h2 a, h2 b, float c) {
  return __builtin_amdgcn_fdot2(a, b, c, false);
}
__device__ __forceinline__ float lrelu(float x) { return x > 0.f ? x : 0.01f * x; }

struct P {
  const float *obs, *pol, *act;
  const float *kw1w, *kw1b, *kw2w, *kw2b, *qw1w, *qw1b, *qw2w, *qw2b;
  const float *ko1w, *ko1b, *ko2w, *ko2b, *qo1w, *qo1b, *qo2w, *qo2b;
  const float *av1w, *av1b, *av2w, *av2b, *fv1w, *fv1b, *fv2w, *fv2b;
  float *out0, *out1, *out2;
  float *wsig, *wo;   // workspace
};

// ======================= K1: f16x2 MFMA front =======================

struct alignas(16) SM1 {
  f16 WAh[64 * 72], WAl[64 * 72];          // weight slot (hi/lo)
  f16 obsh[16 * 72], obsl[16 * 72];
  f16 X1h[16 * 72], X1l[16 * 72];          // kw-hid -> key_o
  f16 X2h[16 * 72], X2l[16 * 72];          // qw-hid -> ko1-hid
  float S2[16 * 68], S3[16 * 68];          // key_z->ck, query_z
  float G2[16 * 68];                       // Gqo [t][j*4+g]
  float wz[512];                           // wzko then wzqo layouts
  float bias8[8 * 64];
  float pi[128], act[128], wsig[256], wo[256], c0[16], e[256];
};

// D = A(16xK) * B^T with K=64 split in 2 ks, f16x2 3-term. A rows = agents, B rows = outs.
__device__ __forceinline__ v4f gemm_tile(const f16* Xh, const f16* Xl,
                                         const f16* Wh, const f16* Wl,
                                         float bv, int nt, int lane) {
  const int m = lane & 15, q = lane >> 4;
  v4f acc = {bv, bv, bv, bv};
  const v8h ah0 = *(const v8h*)(Xh + m * 72 + q * 8);
  const v8h ah1 = *(const v8h*)(Xh + m * 72 + 32 + q * 8);
  const v8h al0 = *(const v8h*)(Xl + m * 72 + q * 8);
  const v8h al1 = *(const v8h*)(Xl + m * 72 + 32 + q * 8);
  const f16* wr = Wh + (nt * 16 + m) * 72 + q * 8;
  const v8h bh0 = *(const v8h*)(wr);
  const v8h bh1 = *(const v8h*)(wr + 32);
  const f16* wr2 = Wl + (nt * 16 + m) * 72 + q * 8;
  const v8h bl0 = *(const v8h*)(wr2);
  const v8h bl1 = *(const v8h*)(wr2 + 32);
  acc = __builtin_amdgcn_mfma_f32_16x16x32_f16(ah0, bh0, acc, 0, 0, 0);
  acc = __builtin_amdgcn_mfma_f32_16x16x32_f16(ah1, bh1, acc, 0, 0, 0);
  acc = __builtin_amdgcn_mfma_f32_16x16x32_f16(ah0, bl0, acc, 0, 0, 0);
  acc = __builtin_amdgcn_mfma_f32_16x16x32_f16(ah1, bl1, acc, 0, 0, 0);
  acc = __builtin_amdgcn_mfma_f32_16x16x32_f16(al0, bh0, acc, 0, 0, 0);
  acc = __builtin_amdgcn_mfma_f32_16x16x32_f16(al1, bh1, acc, 0, 0, 0);
  return acc;
}

__device__ __forceinline__ void writeX(f16* Xh, f16* Xl, v4f acc, int nt, int lane, bool relu) {
  const int m = lane & 15, q = lane >> 4;
#pragma unroll
  for (int reg = 0; reg < 4; reg++) {
    float y = acc[reg];
    if (relu) y = lrelu(y);
    const f16 yh = (f16)y;
    Xh[(q * 4 + reg) * 72 + nt * 16 + m] = yh;
    Xl[(q * 4 + reg) * 72 + nt * 16 + m] = (f16)(y - (float)yh);
  }
}

__device__ __forceinline__ void putW(f16* Wh, f16* Wl, float4 v, int o, int r) {
  h2* dh = (h2*)(Wh + o * 72 + 4 * r);
  h2* dl = (h2*)(Wl + o * 72 + 4 * r);
  const f16 hx = (f16)v.x, hy = (f16)v.y, hz = (f16)v.z, hw = (f16)v.w;
  dh[0] = h2{hx, hy};
  dh[1] = h2{hz, hw};
  dl[0] = h2{(f16)(v.x - (float)hx), (f16)(v.y - (float)hy)};
  dl[1] = h2{(f16)(v.z - (float)hz), (f16)(v.w - (float)hw)};
}

__global__ __launch_bounds__(1024) void critic_k1(P p) {
  __shared__ SM1 s;
  const int tid = threadIdx.x;
  const int b = blockIdx.x;
  const int o = tid & 63, r = tid >> 6;
  const int w = r, lane = tid & 63, m = lane & 15, quad = lane >> 4;

  // ---- register prefetch (all global loads issued once) ----
  const float4 Rkw1 = *(const float4*)(p.kw1w + o * 64 + 4 * r);
  const float4 Rkw2 = *(const float4*)(p.kw2w + o * 64 + 4 * r);
  const float4 Rqw1 = *(const float4*)(p.qw1w + o * 64 + 4 * r);
  const float4 Rqw2 = *(const float4*)(p.qw2w + o * 64 + 4 * r);
  const float4 Rko2 = *(const float4*)(p.ko2w + o * 64 + 4 * r);
  const float4 Rko1 = *(const float4*)(p.ko1w + o * 72 + 4 * r);
  const float4 Rqo1 = *(const float4*)(p.qo1w + o * 72 + 4 * r);
  float4 Rqo2;  // transposed: M[o][4r..4r+3] = qo2w[4r+c][o]
  Rqo2.x = p.qo2w[(4 * r + 0) * 64 + o];
  Rqo2.y = p.qo2w[(4 * r + 1) * 64 + o];
  Rqo2.z = p.qo2w[(4 * r + 2) * 64 + o];
  Rqo2.w = p.qo2w[(4 * r + 3) * 64 + o];
  const float Bqo2v = p.qo2b[o];
  float Rwzqo = 0.f;
  if (tid < 512) Rwzqo = p.qo1w[(tid >> 3) * 72 + 64 + (tid & 7)];

  // ---- P0: stage inputs, biases, wz(=wzko), WA=kw1 ----
  if (tid < 512) {
    const float2 ov = ((const float2*)(p.obs + (size_t)b * 1024))[tid];
    const int e0 = 2 * tid, r0 = e0 >> 6, c0 = e0 & 63;
    const f16 hx = (f16)ov.x, hy = (f16)ov.y;
    *(h2*)(s.obsh + r0 * 72 + c0) = h2{hx, hy};
    *(h2*)(s.obsl + r0 * 72 + c0) = h2{(f16)(ov.x - (float)hx), (f16)(ov.y - (float)hy)};
  }
  if (tid < 128) s.pi[tid] = p.pol[(size_t)b * 128 + tid];
  else if (tid < 256) s.act[tid - 128] = p.act[(size_t)b * 128 + tid - 128];
  if (tid < 64) {
    s.bias8[tid] = p.kw1b[tid];        s.bias8[64 + tid] = p.kw2b[tid];
    s.bias8[128 + tid] = p.qw1b[tid];  s.bias8[192 + tid] = p.qw2b[tid];
    s.bias8[256 + tid] = p.ko1b[tid];  s.bias8[320 + tid] = p.ko2b[tid];
    s.bias8[384 + tid] = p.qo1b[tid];
  }
  if (tid < 512) s.wz[tid] = p.ko1w[(tid >> 3) * 72 + 64 + (tid & 7)];   // wzko [o][c]
  putW(s.WAh, s.WAl, Rkw1, o, r);
  __syncthreads();

  // ---- P1: kw1 hidden -> X1 ----
  if (w < 4) {
    v4f a = gemm_tile(s.obsh, s.obsl, s.WAh, s.WAl, s.bias8[w * 16 + m], w, lane);
    writeX(s.X1h, s.X1l, a, w, lane, true);
  }
  __syncthreads();
  putW(s.WAh, s.WAl, Rkw2, o, r);   // P2
  __syncthreads();
  // ---- P3: key_z -> S2 (f32) ----
  if (w < 4) {
    v4f a = gemm_tile(s.X1h, s.X1l, s.WAh, s.WAl, s.bias8[64 + w * 16 + m], w, lane);
#pragma unroll
    for (int reg = 0; reg < 4; reg++) s.S2[(quad * 4 + reg) * 68 + w * 16 + m] = a[reg];
  }
  __syncthreads();
  putW(s.WAh, s.WAl, Rqw1, o, r);   // P4
  __syncthreads();
  // ---- P5: qw1 hidden -> X2 ----
  if (w < 4) {
    v4f a = gemm_tile(s.obsh, s.obsl, s.WAh, s.WAl, s.bias8[128 + w * 16 + m], w, lane);
    writeX(s.X2h, s.X2l, a, w, lane, true);
  }
  __syncthreads();
  putW(s.WAh, s.WAl, Rqw2, o, r);   // P6
  __syncthreads();
  // ---- P7: query_z -> S3 (f32) ----
  if (w < 4) {
    v4f a = gemm_tile(s.X2h, s.X2l, s.WAh, s.WAl, s.bias8[192 + w * 16 + m], w, lane);
#pragma unroll
    for (int reg = 0; reg < 4; reg++) s.S3[(quad * 4 + reg) * 68 + w * 16 + m] = a[reg];
  }
  __syncthreads();

  // ---- P8: score + sigmoid (VALU) ; stage WA=ko1 ----
  {
    const int j = (tid >> 2) & 15, g = tid & 3;
    float a0 = 0.f, a1 = 0.f, a2 = 0.f, a3 = 0.f;
#pragma unroll
    for (int t4 = 0; t4 < 4; t4++) {
      const float4 qv = *(const float4*)(s.S3 + r * 68 + g * 16 + 4 * t4);
      const float4 kv = *(const float4*)(s.S2 + j * 68 + g * 16 + 4 * t4);
      a0 += qv.x * kv.x; a1 += qv.y * kv.y; a2 += qv.z * kv.z; a3 += qv.w * kv.w;
    }
    float sc = (a0 + a1) + (a2 + a3);
    sc += __shfl_xor(sc, 1);
    sc += __shfl_xor(sc, 2);
    if (g == 0) {
      const float wv = 1.f / (1.f + __expf(-sc * 0.125f));
      s.wsig[r * 16 + j] = wv;
      p.out1[(size_t)b * 256 + r * 16 + j] = wv;
      p.wsig[(size_t)b * 256 + r * 16 + j] = wv;
    }
    putW(s.WAh, s.WAl, Rko1, o, r);
  }
  __syncthreads();

  // ---- P9: ko1 hidden (obs-part MFMA + z-part VALU) -> X2 ----
  if (w < 4) {
    v4f a = gemm_tile(s.obsh, s.obsl, s.WAh, s.WAl, s.bias8[256 + w * 16 + m], w, lane);
    const int oo = w * 16 + m;
    float wzv[8];
    *(float4*)wzv = *(const float4*)(s.wz + oo * 8);
    *(float4*)(wzv + 4) = *(const float4*)(s.wz + oo * 8 + 4);
#pragma unroll
    for (int reg = 0; reg < 4; reg++) {
      const int rr = quad * 4 + reg;
      const float wrr = s.wsig[rr * 16 + rr];
      float zp = 0.f;
#pragma unroll
      for (int c = 0; c < 8; c++) {
        const float zc = s.pi[rr * 8 + c] + wrr * (s.act[rr * 8 + c] - s.pi[rr * 8 + c]);
        zp += wzv[c] * zc;
      }
      const float y = lrelu(a[reg] + zp);
      const f16 yh = (f16)y;
      s.X2h[rr * 72 + oo] = yh;
      s.X2l[rr * 72 + oo] = (f16)(y - (float)yh);
    }
  }
  __syncthreads();
  putW(s.WAh, s.WAl, Rko2, o, r);   // P10
  __syncthreads();
  // ---- P11: key_o -> X1 (no relu) ----
  if (w < 4) {
    v4f a = gemm_tile(s.X2h, s.X2l, s.WAh, s.WAl, s.bias8[320 + w * 16 + m], w, lane);
    writeX(s.X1h, s.X1l, a, w, lane, false);
  }
  __syncthreads();
  putW(s.WAh, s.WAl, Rqo2, o, r);   // P12 (qo2^T)
  __syncthreads();
  // ---- P13: ck -> S2 (no bias) ; c0 via shuffle ----
  if (w < 4) {
    v4f a = gemm_tile(s.X1h, s.X1l, s.WAh, s.WAl, 0.f, w, lane);
#pragma unroll
    for (int reg = 0; reg < 4; reg++) s.S2[(quad * 4 + reg) * 68 + w * 16 + m] = a[reg];
  }
  {
    const float kv = (float)s.X1h[r * 72 + o] + (float)s.X1l[r * 72 + o];
    float t = kv * Bqo2v;
#pragma unroll
    for (int mm = 1; mm < 64; mm <<= 1) t += __shfl_xor(t, mm);
    if (o == 0) s.c0[r] = t;
  }
  __syncthreads();
  // ---- P14: stage WA=qo1(obs-part) + wz=wzqo ----
  putW(s.WAh, s.WAl, Rqo1, o, r);
  if (tid < 512) {
    const int oo = tid >> 3, c = tid & 7;
    s.wz[(oo & 15) * 32 + (oo >> 4) * 8 + c] = Rwzqo;
  }
  __syncthreads();
  // ---- P15: Gqo -> G2 [t][j*4+g] ----
  if (w < 4) {
    v4f a = gemm_tile(s.obsh, s.obsl, s.WAh, s.WAl, s.bias8[384 + w * 16 + m], w, lane);
#pragma unroll
    for (int reg = 0; reg < 4; reg++) s.G2[m * 68 + (quad * 4 + reg) * 4 + w] = a[reg];
  }
  __syncthreads();

  // ---- P16: qo-score -> e ----
  {
    const int j = (tid >> 2) & 15, g = tid & 3;
    const float wij = s.wsig[r * 16 + j];
    float z[8];
#pragma unroll
    for (int c = 0; c < 8; c++) z[c] = s.pi[j * 8 + c] + wij * (s.act[j * 8 + c] - s.pi[j * 8 + c]);
    float sc = 0.f;
#pragma unroll
    for (int t = 0; t < 16; t++) {
      const float4 wa = *(const float4*)(s.wz + t * 32 + g * 8);
      const float4 wb = *(const float4*)(s.wz + t * 32 + g * 8 + 4);
      float hv = s.G2[t * 68 + j * 4 + g]
        + wa.x * z[0] + wa.y * z[1] + wa.z * z[2] + wa.w * z[3]
        + wb.x * z[4] + wb.y * z[5] + wb.z * z[6] + wb.w * z[7];
      hv = lrelu(hv);
      sc += s.S2[r * 68 + g * 16 + t] * hv;
    }
    sc += __shfl_xor(sc, 1);
    sc += __shfl_xor(sc, 2);
    if (g == 0) {
      float yv = (sc + s.c0[r]) * 0.125f;
      yv = fminf(fmaxf(yv, -5.f), 5.f);
      s.e[r * 16 + j] = __expf(yv);
    }
  }
  __syncthreads();

  // ---- P17: softmax + outputs ----
  if (tid < 256) {
    const int i = tid >> 4, j = tid & 15;
    float mx = -1e30f;
#pragma unroll
    for (int jj = 0; jj < 16; jj++) mx = fmaxf(mx, s.e[i * 16 + jj]);
    float den = 0.f;
#pragma unroll
    for (int jj = 0; jj < 16; jj++) den += __expf(s.e[i * 16 + jj] - mx);
    const float val = __expf(s.e[i * 16 + j] - mx) / den;
    s.wo[i * 16 + j] = val;
    p.wo[(size_t)b * 256 + tid] = val;
  }
  __syncthreads();
  {
    const int q = tid >> 2, g = tid & 3, k = q & 15;
    *(float4*)(p.out2 + ((size_t)b * 256 + q) * 16 + 4 * g) =
        *(const float4*)(s.wo + k * 16 + 4 * g);
  }
}

// ======================= K2: f16 MFMA back half =======================

struct alignas(16) SMem2 {
  f16 obsH[16][72];
  f16 AOsrcD[16 * 72];
  f16 APT[64 * 24];
  f16 AextH[16 * 40];
  f16 fv2pw[8 * 64];
  f16 slice[8][1536];
  union {
    struct { f16 av1H[64 * 96]; f16 av2H[64 * 72]; } av;
    f16 fv1H[64 * 136];
  } W;
  float pi[16][8], act[16][8], wsig[16][16];
  float av1b[64], av2b[64], fv1b[64], fv2b[8];
};

__device__ __forceinline__ v8h bfrag(const f16* Wm, int stride, int nt, int ks, int lane) {
  const int n = lane & 15, q = lane >> 4;
  return *(const v8h*)(Wm + (nt * 16 + n) * stride + ks * 32 + q * 8);
}

__device__ __forceinline__ void av_mlp(const SMem2& s, f16* Hbuf, v8h az, int lane, v4f acc2[4]) {
  const int m = lane & 15, q = lane >> 4;
  const v8h a0 = *(const v8h*)(&s.obsH[m][q * 8]);
  const v8h a1 = *(const v8h*)(&s.obsH[m][32 + q * 8]);
#pragma unroll
  for (int nt = 0; nt < 4; nt++) {
    const float bv = s.av1b[nt * 16 + m];
    v4f acc = {bv, bv, bv, bv};
    acc = __builtin_amdgcn_mfma_f32_16x16x32_f16(a0, bfrag(s.W.av.av1H, 96, nt, 0, lane), acc, 0, 0, 0);
    acc = __builtin_amdgcn_mfma_f32_16x16x32_f16(a1, bfrag(s.W.av.av1H, 96, nt, 1, lane), acc, 0, 0, 0);
    acc = __builtin_amdgcn_mfma_f32_16x16x32_f16(az, bfrag(s.W.av.av1H, 96, nt, 2, lane), acc, 0, 0, 0);
#pragma unroll
    for (int reg = 0; reg < 4; reg++)
      Hbuf[(q * 4 + reg) * 72 + nt * 16 + m] = (f16)lrelu(acc[reg]);
  }
  const v8h h0 = *(const v8h*)(Hbuf + m * 72 + q * 8);
  const v8h h1 = *(const v8h*)(Hbuf + m * 72 + 32 + q * 8);
#pragma unroll
  for (int nt = 0; nt < 4; nt++) {
    const float bv = s.av2b[nt * 16 + m];
    v4f acc = {bv, bv, bv, bv};
    acc = __builtin_amdgcn_mfma_f32_16x16x32_f16(h0, bfrag(s.W.av.av2H, 72, nt, 0, lane), acc, 0, 0, 0);
    acc = __builtin_amdgcn_mfma_f32_16x16x32_f16(h1, bfrag(s.W.av.av2H, 72, nt, 1, lane), acc, 0, 0, 0);
    acc2[nt] = acc;
  }
}

__global__ __launch_bounds__(512) void critic_k2(P p) {
  __shared__ SMem2 s;
  const int tid = threadIdx.x;
  const int b = blockIdx.x >> 1, ibase = (blockIdx.x & 1) * 8;
  const int w = tid >> 6, lane = tid & 63;
  const int m = lane & 15, quad = lane >> 4;
  const int i = ibase + w;

  // register prefetch: fv1 + av1 + av2 (no mid-kernel global waits)
  float4 rfv[4];
#pragma unroll
  for (int qq = 0; qq < 4; qq++) rfv[qq] = ((const float4*)p.fv1w)[tid * 4 + qq];
  const float4 rav1a = ((const float4*)p.av1w)[tid * 2];
  const float4 rav1b = ((const float4*)p.av1w)[tid * 2 + 1];
  const float rav1c = p.av1w[4096 + tid];
  const float4 rav2a = ((const float4*)p.av2w)[tid * 2];
  const float4 rav2b = ((const float4*)p.av2w)[tid * 2 + 1];

  // ---- stage inputs + av weights ----
  for (int k = tid; k < 1024; k += 512) s.obsH[k >> 6][k & 63] = (f16)p.obs[(size_t)b * 1024 + k];
  if (tid < 128) { s.pi[tid >> 3][tid & 7] = p.pol[(size_t)b * 128 + tid]; }
  else if (tid < 256) { int k = tid - 128; s.act[k >> 3][k & 7] = p.act[(size_t)b * 128 + k]; }
  for (int k = tid; k < 256; k += 512) s.wsig[k >> 4][k & 15] = p.wsig[(size_t)b * 256 + k];
  {
    const int kk = tid >> 5, j2 = tid & 31;
    float v = 0.f;
    if (j2 < 16) v = p.wo[(size_t)b * 256 + kk * 16 + j2] * 0.0625f;
    else if (j2 - 16 == kk) v = p.wo[(size_t)b * 256 + kk * 16 + kk] * 0.0625f;
    s.AextH[kk * 40 + j2] = (f16)v;
  }
  {
    float av1v[8] = {rav1a.x, rav1a.y, rav1a.z, rav1a.w, rav1b.x, rav1b.y, rav1b.z, rav1b.w};
#pragma unroll
    for (int e = 0; e < 8; e++) {
      const int k = tid * 8 + e, rr = k / 72, cc = k - rr * 72;
      s.W.av.av1H[rr * 96 + cc] = (f16)av1v[e];
    }
    const int k = 4096 + tid, rr = k / 72, cc = k - rr * 72;
    s.W.av.av1H[rr * 96 + cc] = (f16)rav1c;
  }
  {
    const int row = tid >> 3, c0 = 72 + (tid & 7) * 3;
#pragma unroll
    for (int c = 0; c < 3; c++) s.W.av.av1H[row * 96 + c0 + c] = (f16)0.f;
  }
  {
    float av2v[8] = {rav2a.x, rav2a.y, rav2a.z, rav2a.w, rav2b.x, rav2b.y, rav2b.z, rav2b.w};
#pragma unroll
    for (int e = 0; e < 8; e++) {
      const int k = tid * 8 + e;
      s.W.av.av2H[(k >> 6) * 72 + (k & 63)] = (f16)av2v[e];
    }
  }
  s.fv2pw[tid] = (f16)p.fv2w[tid];
  if (tid < 64) { s.av1b[tid] = p.av1b[tid]; s.av2b[tid] = p.av2b[tid]; s.fv1b[tid] = p.fv1b[tid]; }
  else if (tid < 72) s.fv2b[tid - 64] = p.fv2b[tid - 64];
  __syncthreads();

  // ---- AO_i per wave ----
  f16* Sl = &s.slice[w][0];
  {
    v8h az = {};
    if (quad == 0) {
      const float wv = s.wsig[i][m];
#pragma unroll
      for (int c = 0; c < 8; c++) az[c] = (f16)(s.pi[m][c] + wv * (s.act[m][c] - s.pi[m][c]));
    }
    v4f acc2[4];
    av_mlp(s, Sl, az, lane, acc2);
#pragma unroll
    for (int nt = 0; nt < 4; nt++)
#pragma unroll
      for (int reg = 0; reg < 4; reg++)
        Sl[(nt * 16 + m) * 24 + quad * 4 + reg] = (f16)acc2[nt][reg];
  }
  if (w == 0) {  // AP rows
    v8h az = {};
    if (quad == 0) {
#pragma unroll
      for (int c = 0; c < 8; c++) az[c] = (f16)s.pi[m][c];
    }
    v4f acc2[4];
    av_mlp(s, s.APT, az, lane, acc2);
#pragma unroll
    for (int nt = 0; nt < 4; nt++)
#pragma unroll
      for (int reg = 0; reg < 4; reg++)
        s.APT[(nt * 16 + m) * 24 + quad * 4 + reg] = (f16)acc2[nt][reg];
  }
  if (w == 1) {  // attn_src rows
    v8h az = {};
    if (quad == 0) {
      const float wv = s.wsig[m][m];
#pragma unroll
      for (int c = 0; c < 8; c++) az[c] = (f16)(s.pi[m][c] + wv * (s.act[m][c] - s.pi[m][c]));
    }
    v4f acc2[4];
    av_mlp(s, s.AOsrcD, az, lane, acc2);
#pragma unroll
    for (int nt = 0; nt < 4; nt++)
#pragma unroll
      for (int reg = 0; reg < 4; reg++)
        s.AOsrcD[(quad * 4 + reg) * 72 + nt * 16 + m] = (f16)acc2[nt][reg];
  }
  __syncthreads();

  // ---- write fv1 from registers ----
#pragma unroll
  for (int qq = 0; qq < 4; qq++) {
    const int e0 = tid * 16 + qq * 4;
    h2* d = (h2*)&s.W.fv1H[(e0 >> 7) * 136 + (e0 & 127)];
    d[0] = h2{(f16)rfv[qq].x, (f16)rfv[qq].y};
    d[1] = h2{(f16)rfv[qq].z, (f16)rfv[qq].w};
  }
  __syncthreads();

  // ---- mixed ----
  {
    const v8h am = *(const v8h*)(&s.AextH[m * 40 + quad * 8]);
    v4f macc[4];
#pragma unroll
    for (int nt = 0; nt < 4; nt++) {
      const int o = nt * 16 + m;
      v8h bf;
      if (quad < 2) {
        bf = *(const v8h*)(Sl + o * 24 + quad * 8);
      } else {
        const v8h apv = *(const v8h*)(&s.APT[o * 24 + (quad - 2) * 8]);
        const v8h aov = *(const v8h*)(Sl + o * 24 + (quad - 2) * 8);
        bf = apv - aov;
      }
      v4f z4 = {0.f, 0.f, 0.f, 0.f};
      macc[nt] = __builtin_amdgcn_mfma_f32_16x16x32_f16(am, bf, z4, 0, 0, 0);
    }
#pragma unroll
    for (int nt = 0; nt < 4; nt++)
#pragma unroll
      for (int reg = 0; reg < 4; reg++)
        Sl[(quad * 4 + reg) * 72 + nt * 16 + m] = (f16)macc[nt][reg];
  }

  // ---- fv1 ----
  {
    const v8h f0 = *(const v8h*)(&s.AOsrcD[m * 72 + quad * 8]);
    const v8h f1 = *(const v8h*)(&s.AOsrcD[m * 72 + 32 + quad * 8]);
    const v8h f2 = *(const v8h*)(Sl + m * 72 + quad * 8);
    const v8h f3 = *(const v8h*)(Sl + m * 72 + 32 + quad * 8);
#pragma unroll
    for (int nt = 0; nt < 4; nt++) {
      const float bv = s.fv1b[nt * 16 + m];
      v4f acc = {bv, bv, bv, bv};
      acc = __builtin_amdgcn_mfma_f32_16x16x32_f16(f0, bfrag(s.W.fv1H, 136, nt, 0, lane), acc, 0, 0, 0);
      acc = __builtin_amdgcn_mfma_f32_16x16x32_f16(f1, bfrag(s.W.fv1H, 136, nt, 1, lane), acc, 0, 0, 0);
      acc = __builtin_amdgcn_mfma_f32_16x16x32_f16(f2, bfrag(s.W.fv1H, 136, nt, 2, lane), acc, 0, 0, 0);
      acc = __builtin_amdgcn_mfma_f32_16x16x32_f16(f3, bfrag(s.W.fv1H, 136, nt, 3, lane), acc, 0, 0, 0);
#pragma unroll
      for (int reg = 0; reg < 4; reg++)
        Sl[(quad * 4 + reg) * 72 + nt * 16 + m] = (f16)lrelu(acc[reg]);
    }
  }
  // ---- fv2 ----
  {
    const int g2 = quad;
    float y0 = s.fv2b[2 * g2], y1 = s.fv2b[2 * g2 + 1];
#pragma unroll
    for (int o2 = 0; o2 < 32; o2++) {
      const h2 hh = *(const h2*)(Sl + m * 72 + 2 * o2);
      const h2 w0 = *(const h2*)(&s.fv2pw[(2 * g2) * 64 + 2 * o2]);
      const h2 w1 = *(const h2*)(&s.fv2pw[(2 * g2 + 1) * 64 + 2 * o2]);
      y0 = fdot2f(w0, hh, y0);
      y1 = fdot2f(w1, hh, y1);
    }
    *(float2*)(p.out0 + ((size_t)b * 256 + i * 16 + m) * 8 + 2 * g2) = make_float2(y0, y1);
  }
}

extern "C" void kernel_launch(void* const* d_in, const int* in_sizes, int n_in,
                              void* d_out, int out_size, void* d_ws, size_t ws_size,
                              hipStream_t stream) {
  P p;
  p.obs = (const float*)d_in[0];
  p.pol = (const float*)d_in[1];
  p.act = (const float*)d_in[2];
  p.kw1w = (const float*)d_in[3];  p.kw1b = (const float*)d_in[4];
  p.kw2w = (const float*)d_in[5];  p.kw2b = (const float*)d_in[6];
  p.qw1w = (const float*)d_in[7];  p.qw1b = (const float*)d_in[8];
  p.qw2w = (const float*)d_in[9];  p.qw2b = (const float*)d_in[10];
  p.ko1w = (const float*)d_in[11]; p.ko1b = (const float*)d_in[12];
  p.ko2w = (const float*)d_in[13]; p.ko2b = (const float*)d_in[14];
  p.qo1w = (const float*)d_in[15]; p.qo1b = (const float*)d_in[16];
  p.qo2w = (const float*)d_in[17]; p.qo2b = (const float*)d_in[18];
  p.av1w = (const float*)d_in[19]; p.av1b = (const float*)d_in[20];
  p.av2w = (const float*)d_in[21]; p.av2b = (const float*)d_in[22];
  p.fv1w = (const float*)d_in[23]; p.fv1b = (const float*)d_in[24];
  p.fv2w = (const float*)d_in[25]; p.fv2b = (const float*)d_in[26];

  const int Bn = in_sizes[0] / (A_ * DOBS_);   // 128
  p.out0 = (float*)d_out;
  p.out1 = p.out0 + (size_t)Bn * A_ * A_ * NA_;
  p.out2 = p.out1 + (size_t)Bn * A_ * A_;
  p.wsig = (float*)d_ws;
  p.wo = p.wsig + (size_t)Bn * 256;

  hipLaunchKernelGGL(critic_k1, dim3(Bn), dim3(1024), 0, stream, p);
  hipLaunchKernelGGL(critic_k2, dim3(2 * Bn), dim3(512), 0, stream, p);
}

// Round 6
// 127.646 us; speedup vs baseline: 1.7820x; 1.0217x over previous
//
#include <hip/hip_runtime.h>

#define A_ 16
#define NA_ 8
#define DOBS_ 64

typedef _Float16 f16;
typedef f16 h2 __attribute__((ext_vector_type(2)));
typedef f16 v8h __attribute__((ext_vector_type(8)));
typedef float v4f __attribute__((ext_vector_type(4)));

__device__ __forceinline__ float fdot2f(h2 a, h2 b, float c) {
  return __builtin_amdgcn_fdot2(a, b, c, false);
}
__device__ __forceinline__ float lrelu(float x) { return x > 0.f ? x : 0.01f * x; }

struct P {
  const float *obs, *pol, *act;
  const float *kw1w, *kw1b, *kw2w, *kw2b, *qw1w, *qw1b, *qw2w, *qw2b;
  const float *ko1w, *ko1b, *ko2w, *ko2b, *qo1w, *qo1b, *qo2w, *qo2b;
  const float *av1w, *av1b, *av2w, *av2b, *fv1w, *fv1b, *fv2w, *fv2b;
  float *out0, *out1, *out2;
};

struct alignas(16) SM {
  // persistent
  f16 obsh[16 * 72];            // 2304 B
  float pi[128];                // 512
  float act[128];               // 512
  float wsig[256];              // 1024
  float wo[256];                // 1024
  float c0[16];                 // 64
  f16 eh[256];                  // 512
  union {
    struct {                    // FRONT (59136 B)
      f16 obsl[16 * 72];
      f16 Wp1[64 * 72], Wp2[64 * 72];   // plain slots; also qo1/qo2T hi+lo
      f16 Wxh[64 * 72], Wxl[64 * 72];   // hi/lo slot (ko1, ko2)
      f16 X1h[16 * 72], X1l[16 * 72];
      f16 X2h[16 * 72], X2l[16 * 72];
      float S2[16 * 68];        // key_z -> ck
      float S3G[16 * 68];       // query_z -> Gqo
      float wz[512];            // wzko -> wzqo
    } f;
    struct {                    // BACK (54536 B)
      f16 AOsrcD[16 * 72];
      f16 APT[64 * 24];
      f16 AextH[16 * 40];
      f16 fv2pw[512];
      f16 slice[8][1536];
      union { struct { f16 av1H[64 * 96]; f16 av2H[64 * 72]; } av; f16 fv1H[64 * 136]; } W;
      float av1b[64], av2b[64], fv1b[64], fv2b[8];
    } bk;
  } u;
};   // total 65088 B

// ---- MFMA helpers (layouts identical to the verified R5 kernels) ----
__device__ __forceinline__ v4f gemm_plain(const f16* Xh, const f16* W, float bv, int nt, int lane) {
  const int m = lane & 15, q = lane >> 4;
  v4f acc = {bv, bv, bv, bv};
  const v8h a0 = *(const v8h*)(Xh + m * 72 + q * 8);
  const v8h a1 = *(const v8h*)(Xh + m * 72 + 32 + q * 8);
  const f16* wr = W + (nt * 16 + m) * 72 + q * 8;
  acc = __builtin_amdgcn_mfma_f32_16x16x32_f16(a0, *(const v8h*)wr, acc, 0, 0, 0);
  acc = __builtin_amdgcn_mfma_f32_16x16x32_f16(a1, *(const v8h*)(wr + 32), acc, 0, 0, 0);
  return acc;
}

__device__ __forceinline__ v4f gemm_tile(const f16* Xh, const f16* Xl,
                                         const f16* Wh, const f16* Wl,
                                         float bv, int nt, int lane) {
  const int m = lane & 15, q = lane >> 4;
  v4f acc = {bv, bv, bv, bv};
  const v8h ah0 = *(const v8h*)(Xh + m * 72 + q * 8);
  const v8h ah1 = *(const v8h*)(Xh + m * 72 + 32 + q * 8);
  const v8h al0 = *(const v8h*)(Xl + m * 72 + q * 8);
  const v8h al1 = *(const v8h*)(Xl + m * 72 + 32 + q * 8);
  const f16* wr = Wh + (nt * 16 + m) * 72 + q * 8;
  const v8h bh0 = *(const v8h*)(wr);
  const v8h bh1 = *(const v8h*)(wr + 32);
  const f16* wr2 = Wl + (nt * 16 + m) * 72 + q * 8;
  const v8h bl0 = *(const v8h*)(wr2);
  const v8h bl1 = *(const v8h*)(wr2 + 32);
  acc = __builtin_amdgcn_mfma_f32_16x16x32_f16(ah0, bh0, acc, 0, 0, 0);
  acc = __builtin_amdgcn_mfma_f32_16x16x32_f16(ah1, bh1, acc, 0, 0, 0);
  acc = __builtin_amdgcn_mfma_f32_16x16x32_f16(ah0, bl0, acc, 0, 0, 0);
  acc = __builtin_amdgcn_mfma_f32_16x16x32_f16(ah1, bl1, acc, 0, 0, 0);
  acc = __builtin_amdgcn_mfma_f32_16x16x32_f16(al0, bh0, acc, 0, 0, 0);
  acc = __builtin_amdgcn_mfma_f32_16x16x32_f16(al1, bh1, acc, 0, 0, 0);
  return acc;
}

__device__ __forceinline__ void writeX(f16* Xh, f16* Xl, v4f acc, int nt, int lane, bool relu) {
  const int m = lane & 15, q = lane >> 4;
#pragma unroll
  for (int reg = 0; reg < 4; reg++) {
    float y = acc[reg];
    if (relu) y = lrelu(y);
    const f16 yh = (f16)y;
    Xh[(q * 4 + reg) * 72 + nt * 16 + m] = yh;
    Xl[(q * 4 + reg) * 72 + nt * 16 + m] = (f16)(y - (float)yh);
  }
}

__device__ __forceinline__ void putP(f16* W, float4 v, int o, int rq) {
  h2* d = (h2*)(W + o * 72 + 4 * rq);
  d[0] = h2{(f16)v.x, (f16)v.y};
  d[1] = h2{(f16)v.z, (f16)v.w};
}

__device__ __forceinline__ void putW(f16* Wh, f16* Wl, float4 v, int o, int rq) {
  h2* dh = (h2*)(Wh + o * 72 + 4 * rq);
  h2* dl = (h2*)(Wl + o * 72 + 4 * rq);
  const f16 hx = (f16)v.x, hy = (f16)v.y, hz = (f16)v.z, hw = (f16)v.w;
  dh[0] = h2{hx, hy};
  dh[1] = h2{hz, hw};
  dl[0] = h2{(f16)(v.x - (float)hx), (f16)(v.y - (float)hy)};
  dl[1] = h2{(f16)(v.z - (float)hz), (f16)(v.w - (float)hw)};
}

__device__ __forceinline__ v8h bfrag(const f16* Wm, int stride, int nt, int ks, int lane) {
  const int n = lane & 15, q = lane >> 4;
  return *(const v8h*)(Wm + (nt * 16 + n) * stride + ks * 32 + q * 8);
}

__device__ __forceinline__ void av_mlp2(const f16* obsh, const f16* av1H, const f16* av2H,
                                        const float* av1b, const float* av2b,
                                        f16* Hbuf, v8h az, int lane, v4f acc2[4]) {
  const int m = lane & 15, q = lane >> 4;
  const v8h a0 = *(const v8h*)(obsh + m * 72 + q * 8);
  const v8h a1 = *(const v8h*)(obsh + m * 72 + 32 + q * 8);
#pragma unroll
  for (int nt = 0; nt < 4; nt++) {
    const float bv = av1b[nt * 16 + m];
    v4f acc = {bv, bv, bv, bv};
    acc = __builtin_amdgcn_mfma_f32_16x16x32_f16(a0, bfrag(av1H, 96, nt, 0, lane), acc, 0, 0, 0);
    acc = __builtin_amdgcn_mfma_f32_16x16x32_f16(a1, bfrag(av1H, 96, nt, 1, lane), acc, 0, 0, 0);
    acc = __builtin_amdgcn_mfma_f32_16x16x32_f16(az, bfrag(av1H, 96, nt, 2, lane), acc, 0, 0, 0);
#pragma unroll
    for (int reg = 0; reg < 4; reg++)
      Hbuf[(q * 4 + reg) * 72 + nt * 16 + m] = (f16)lrelu(acc[reg]);
  }
  const v8h h0 = *(const v8h*)(Hbuf + m * 72 + q * 8);
  const v8h h1 = *(const v8h*)(Hbuf + m * 72 + 32 + q * 8);
#pragma unroll
  for (int nt = 0; nt < 4; nt++) {
    const float bv = av2b[nt * 16 + m];
    v4f acc = {bv, bv, bv, bv};
    acc = __builtin_amdgcn_mfma_f32_16x16x32_f16(h0, bfrag(av2H, 72, nt, 0, lane), acc, 0, 0, 0);
    acc = __builtin_amdgcn_mfma_f32_16x16x32_f16(h1, bfrag(av2H, 72, nt, 1, lane), acc, 0, 0, 0);
    acc2[nt] = acc;
  }
}

__global__ __launch_bounds__(512) void critic_fused(P p) {
  __shared__ SM s;
  const int tid = threadIdx.x;
  const int b = blockIdx.x >> 1, ihalf = blockIdx.x & 1;
  const int w = tid >> 6, lane = tid & 63;
  const int m = lane & 15, quad = lane >> 4;
  const int o = tid & 63, r8 = tid >> 6;

  // ================= register prefetch (single global-latency exposure) =================
  float4 Rkw1[2], Rkw2[2], Rqw1[2], Rqw2[2], Rko2[2], Rko1[2], Rqo1[2], Rqo2[2];
#pragma unroll
  for (int h = 0; h < 2; h++) {
    const int rq = r8 + 8 * h;
    Rkw1[h] = *(const float4*)(p.kw1w + o * 64 + 4 * rq);
    Rkw2[h] = *(const float4*)(p.kw2w + o * 64 + 4 * rq);
    Rqw1[h] = *(const float4*)(p.qw1w + o * 64 + 4 * rq);
    Rqw2[h] = *(const float4*)(p.qw2w + o * 64 + 4 * rq);
    Rko2[h] = *(const float4*)(p.ko2w + o * 64 + 4 * rq);
    Rko1[h] = *(const float4*)(p.ko1w + o * 72 + 4 * rq);
    Rqo1[h] = *(const float4*)(p.qo1w + o * 72 + 4 * rq);
    Rqo2[h].x = p.qo2w[(4 * rq + 0) * 64 + o];
    Rqo2[h].y = p.qo2w[(4 * rq + 1) * 64 + o];
    Rqo2[h].z = p.qo2w[(4 * rq + 2) * 64 + o];
    Rqo2[h].w = p.qo2w[(4 * rq + 3) * 64 + o];
  }
  const float Rwzko = p.ko1w[(tid >> 3) * 72 + 64 + (tid & 7)];
  const float Rwzqo = p.qo1w[(tid >> 3) * 72 + 64 + (tid & 7)];
  const int bi = (w & 3) * 16 + m;
  const float bias1 = (w < 4 ? p.kw1b : p.qw1b)[bi];
  const float bias2 = (w < 4 ? p.kw2b : p.qw2b)[bi];
  const float bias3 = (w < 4 ? p.ko1b : p.qo1b)[bi];
  const float bias4 = p.ko2b[bi];
  const float Bqo2_0 = p.qo2b[tid & 31];
  const float Bqo2_1 = p.qo2b[(tid & 31) + 32];
  // back-half weights
  const float4 rav1a = ((const float4*)p.av1w)[tid * 2];
  const float4 rav1b = ((const float4*)p.av1w)[tid * 2 + 1];
  const float rav1c = p.av1w[4096 + tid];
  const float4 rav2a = ((const float4*)p.av2w)[tid * 2];
  const float4 rav2b = ((const float4*)p.av2w)[tid * 2 + 1];
  float4 rfv[4];
#pragma unroll
  for (int qq = 0; qq < 4; qq++) rfv[qq] = ((const float4*)p.fv1w)[tid * 4 + qq];
  const float rfv2 = p.fv2w[tid];
  float rb1 = 0.f, rb2 = 0.f, rb3 = 0.f, rb4 = 0.f;
  if (tid < 64) { rb1 = p.av1b[tid]; rb2 = p.av2b[tid]; rb3 = p.fv1b[tid]; }
  if (tid < 8) rb4 = p.fv2b[tid];

  // ================= P0: inputs + kw1/qw1 + ko1 =================
  {
    const float2 ov = ((const float2*)(p.obs + (size_t)b * 1024))[tid];
    const int e0 = 2 * tid, r0 = e0 >> 6, c0i = e0 & 63;
    const f16 hx = (f16)ov.x, hy = (f16)ov.y;
    *(h2*)(s.obsh + r0 * 72 + c0i) = h2{hx, hy};
    *(h2*)(s.u.f.obsl + r0 * 72 + c0i) = h2{(f16)(ov.x - (float)hx), (f16)(ov.y - (float)hy)};
  }
  if (tid < 128) s.pi[tid] = p.pol[(size_t)b * 128 + tid];
  else if (tid < 256) s.act[tid - 128] = p.act[(size_t)b * 128 + tid - 128];
  s.u.f.wz[tid] = Rwzko;
  putP(s.u.f.Wp1, Rkw1[0], o, r8); putP(s.u.f.Wp1, Rkw1[1], o, r8 + 8);
  putP(s.u.f.Wp2, Rqw1[0], o, r8); putP(s.u.f.Wp2, Rqw1[1], o, r8 + 8);
  putW(s.u.f.Wxh, s.u.f.Wxl, Rko1[0], o, r8); putW(s.u.f.Wxh, s.u.f.Wxl, Rko1[1], o, r8 + 8);
  __syncthreads();

  // ---- P1: dual hidden (waves 0-3 kw1, 4-7 qw1) ----
  {
    const f16* Wp = (w < 4) ? s.u.f.Wp1 : s.u.f.Wp2;
    f16* Xo = (w < 4) ? s.u.f.X1h : s.u.f.X2h;
    v4f a = gemm_plain(s.obsh, Wp, bias1, w & 3, lane);
#pragma unroll
    for (int reg = 0; reg < 4; reg++)
      Xo[(quad * 4 + reg) * 72 + (w & 3) * 16 + m] = (f16)lrelu(a[reg]);
  }
  __syncthreads();
  putP(s.u.f.Wp1, Rkw2[0], o, r8); putP(s.u.f.Wp1, Rkw2[1], o, r8 + 8);
  putP(s.u.f.Wp2, Rqw2[0], o, r8); putP(s.u.f.Wp2, Rqw2[1], o, r8 + 8);
  __syncthreads();

  // ---- P3: key_z (waves 0-3) / query_z (4-7) ----
  {
    const f16* Wp = (w < 4) ? s.u.f.Wp1 : s.u.f.Wp2;
    const f16* Xi = (w < 4) ? s.u.f.X1h : s.u.f.X2h;
    float* So = (w < 4) ? s.u.f.S2 : s.u.f.S3G;
    v4f a = gemm_plain(Xi, Wp, bias2, w & 3, lane);
#pragma unroll
    for (int reg = 0; reg < 4; reg++)
      So[(quad * 4 + reg) * 68 + (w & 3) * 16 + m] = a[reg];
  }
  __syncthreads();

  // ---- P4: score + sigmoid ; stage Wp=qo1 hi/lo ----
  {
    const int idx = tid >> 1, g2 = tid & 1;
    const int i = idx >> 4, j = idx & 15;
    float a0 = 0.f, a1 = 0.f, a2 = 0.f, a3 = 0.f;
#pragma unroll
    for (int t4 = 0; t4 < 8; t4++) {
      const float4 qv = *(const float4*)(s.u.f.S3G + i * 68 + g2 * 32 + 4 * t4);
      const float4 kv = *(const float4*)(s.u.f.S2 + j * 68 + g2 * 32 + 4 * t4);
      a0 += qv.x * kv.x; a1 += qv.y * kv.y; a2 += qv.z * kv.z; a3 += qv.w * kv.w;
    }
    float sc = (a0 + a1) + (a2 + a3);
    sc += __shfl_xor(sc, 1);
    if (g2 == 0) {
      const float wv = 1.f / (1.f + __expf(-sc * 0.125f));
      s.wsig[idx] = wv;
      p.out1[(size_t)b * 256 + idx] = wv;
    }
    putW(s.u.f.Wp1, s.u.f.Wp2, Rqo1[0], o, r8);
    putW(s.u.f.Wp1, s.u.f.Wp2, Rqo1[1], o, r8 + 8);
  }
  __syncthreads();

  // ---- P5: ko1-hid (waves 0-3, 6-term + z) ; Gqo (waves 4-7, 6-term) ----
  if (w < 4) {
    v4f a = gemm_tile(s.obsh, s.u.f.obsl, s.u.f.Wxh, s.u.f.Wxl, bias3, w, lane);
    const int oo = w * 16 + m;
    float wzv[8];
    *(float4*)wzv = *(const float4*)(s.u.f.wz + oo * 8);
    *(float4*)(wzv + 4) = *(const float4*)(s.u.f.wz + oo * 8 + 4);
#pragma unroll
    for (int reg = 0; reg < 4; reg++) {
      const int rr = quad * 4 + reg;
      const float wrr = s.wsig[rr * 16 + rr];
      float zp = 0.f;
#pragma unroll
      for (int c = 0; c < 8; c++) {
        const float zc = s.pi[rr * 8 + c] + wrr * (s.act[rr * 8 + c] - s.pi[rr * 8 + c]);
        zp += wzv[c] * zc;
      }
      const float y = lrelu(a[reg] + zp);
      const f16 yh = (f16)y;
      s.u.f.X2h[rr * 72 + oo] = yh;
      s.u.f.X2l[rr * 72 + oo] = (f16)(y - (float)yh);
    }
  } else {
    v4f a = gemm_tile(s.obsh, s.u.f.obsl, s.u.f.Wp1, s.u.f.Wp2, bias3, w - 4, lane);
#pragma unroll
    for (int reg = 0; reg < 4; reg++)
      s.u.f.S3G[m * 68 + (quad * 4 + reg) * 4 + (w - 4)] = a[reg];   // G[o=g*16+t][j]
  }
  __syncthreads();

  // ---- P6: restage Wx=ko2, Wp=qo2T, wz=wzqo ----
  putW(s.u.f.Wxh, s.u.f.Wxl, Rko2[0], o, r8); putW(s.u.f.Wxh, s.u.f.Wxl, Rko2[1], o, r8 + 8);
  putW(s.u.f.Wp1, s.u.f.Wp2, Rqo2[0], o, r8); putW(s.u.f.Wp1, s.u.f.Wp2, Rqo2[1], o, r8 + 8);
  { const int oo = tid >> 3, c = tid & 7; s.u.f.wz[(oo & 15) * 32 + (oo >> 4) * 8 + c] = Rwzqo; }
  __syncthreads();

  // ---- P7: key_o -> X1 ----
  if (w < 4) {
    v4f a = gemm_tile(s.u.f.X2h, s.u.f.X2l, s.u.f.Wxh, s.u.f.Wxl, bias4, w, lane);
    writeX(s.u.f.X1h, s.u.f.X1l, a, w, lane, false);
  }
  __syncthreads();

  // ---- P8: ck -> S2 ; c0 ----
  if (w < 4) {
    v4f a = gemm_tile(s.u.f.X1h, s.u.f.X1l, s.u.f.Wp1, s.u.f.Wp2, 0.f, w, lane);
#pragma unroll
    for (int reg = 0; reg < 4; reg++)
      s.u.f.S2[(quad * 4 + reg) * 68 + w * 16 + m] = a[reg];
  }
  {
    const int rr = tid >> 5, cc = tid & 31;
    const float kv0 = (float)s.u.f.X1h[rr * 72 + cc] + (float)s.u.f.X1l[rr * 72 + cc];
    const float kv1 = (float)s.u.f.X1h[rr * 72 + cc + 32] + (float)s.u.f.X1l[rr * 72 + cc + 32];
    float t = kv0 * Bqo2_0 + kv1 * Bqo2_1;
#pragma unroll
    for (int mk = 1; mk < 32; mk <<= 1) t += __shfl_xor(t, mk);
    if (cc == 0) s.c0[rr] = t;
  }
  __syncthreads();

  // ---- P9: qo-score -> e ----
  {
    const int idx = tid >> 1, g2 = tid & 1;
    const int i = idx >> 4, j = idx & 15;
    const float wij = s.wsig[i * 16 + j];
    float z[8];
#pragma unroll
    for (int c = 0; c < 8; c++) z[c] = s.pi[j * 8 + c] + wij * (s.act[j * 8 + c] - s.pi[j * 8 + c]);
    float sc = 0.f;
#pragma unroll
    for (int gg = 2 * g2; gg <= 2 * g2 + 1; gg++) {
#pragma unroll
      for (int t = 0; t < 16; t++) {
        const float4 wa = *(const float4*)(s.u.f.wz + t * 32 + gg * 8);
        const float4 wb = *(const float4*)(s.u.f.wz + t * 32 + gg * 8 + 4);
        float hv = s.u.f.S3G[t * 68 + j * 4 + gg]
          + wa.x * z[0] + wa.y * z[1] + wa.z * z[2] + wa.w * z[3]
          + wb.x * z[4] + wb.y * z[5] + wb.z * z[6] + wb.w * z[7];
        hv = lrelu(hv);
        sc += s.u.f.S2[i * 68 + gg * 16 + t] * hv;
      }
    }
    sc += __shfl_xor(sc, 1);
    if (g2 == 0) {
      float yv = (sc + s.c0[i]) * 0.125f;
      yv = fminf(fmaxf(yv, -5.f), 5.f);
      s.eh[idx] = (f16)__expf(yv);
    }
  }
  __syncthreads();

  // ---- P10a: softmax -> wo ; stage back weights (overlays dead front scratch) ----
  if (tid < 256) {
    const int i = tid >> 4, j = tid & 15;
    float ev[16]; float mx = -1e30f;
#pragma unroll
    for (int jj = 0; jj < 16; jj++) { ev[jj] = (float)s.eh[i * 16 + jj]; mx = fmaxf(mx, ev[jj]); }
    float den = 0.f;
#pragma unroll
    for (int jj = 0; jj < 16; jj++) den += __expf(ev[jj] - mx);
    s.wo[tid] = __expf(ev[j] - mx) / den;
  }
  {
    float av1v[8] = {rav1a.x, rav1a.y, rav1a.z, rav1a.w, rav1b.x, rav1b.y, rav1b.z, rav1b.w};
#pragma unroll
    for (int e = 0; e < 8; e++) {
      const int k = tid * 8 + e, rr = k / 72, cc = k - rr * 72;
      s.u.bk.W.av.av1H[rr * 96 + cc] = (f16)av1v[e];
    }
    const int k = 4096 + tid, rr = k / 72, cc = k - rr * 72;
    s.u.bk.W.av.av1H[rr * 96 + cc] = (f16)rav1c;
    const int row = tid >> 3, c0p = 72 + (tid & 7) * 3;
#pragma unroll
    for (int c = 0; c < 3; c++) s.u.bk.W.av.av1H[row * 96 + c0p + c] = (f16)0.f;
    float av2v[8] = {rav2a.x, rav2a.y, rav2a.z, rav2a.w, rav2b.x, rav2b.y, rav2b.z, rav2b.w};
#pragma unroll
    for (int e = 0; e < 8; e++) {
      const int k2 = tid * 8 + e;
      s.u.bk.W.av.av2H[(k2 >> 6) * 72 + (k2 & 63)] = (f16)av2v[e];
    }
    s.u.bk.fv2pw[tid] = (f16)rfv2;
    if (tid < 64) { s.u.bk.av1b[tid] = rb1; s.u.bk.av2b[tid] = rb2; s.u.bk.fv1b[tid] = rb3; }
    if (tid < 8) s.u.bk.fv2b[tid] = rb4;
  }
  __syncthreads();

  // ---- P10b: AextH + out2 ----
  {
    const int kk = tid >> 5, j2 = tid & 31;
    float v = 0.f;
    if (j2 < 16) v = s.wo[kk * 16 + j2] * 0.0625f;
    else if (j2 - 16 == kk) v = s.wo[kk * 16 + kk] * 0.0625f;
    s.u.bk.AextH[kk * 40 + j2] = (f16)v;
    const int q_ = tid >> 1, g2_ = tid & 1, k_ = q_ & 15;
    float* dst = p.out2 + ((size_t)b * 256 + q_) * 16 + 8 * g2_;
    *(float4*)(dst) = *(const float4*)(s.wo + k_ * 16 + 8 * g2_);
    *(float4*)(dst + 4) = *(const float4*)(s.wo + k_ * 16 + 8 * g2_ + 4);
  }
  __syncthreads();

  // ---- P11: AO (all 8 waves, i = ihalf*8+w) + AP (wave0) + attn_src (wave1) ----
  const int i_ = ihalf * 8 + w;
  f16* Sl = &s.u.bk.slice[w][0];
  {
    v8h az = {};
    if (quad == 0) {
      const float wv = s.wsig[i_ * 16 + m];
#pragma unroll
      for (int c = 0; c < 8; c++)
        az[c] = (f16)(s.pi[m * 8 + c] + wv * (s.act[m * 8 + c] - s.pi[m * 8 + c]));
    }
    v4f acc2[4];
    av_mlp2(s.obsh, s.u.bk.W.av.av1H, s.u.bk.W.av.av2H, s.u.bk.av1b, s.u.bk.av2b, Sl, az, lane, acc2);
#pragma unroll
    for (int nt = 0; nt < 4; nt++)
#pragma unroll
      for (int reg = 0; reg < 4; reg++)
        Sl[(nt * 16 + m) * 24 + quad * 4 + reg] = (f16)acc2[nt][reg];
  }
  if (w == 0) {
    v8h az = {};
    if (quad == 0) {
#pragma unroll
      for (int c = 0; c < 8; c++) az[c] = (f16)s.pi[m * 8 + c];
    }
    v4f acc2[4];
    av_mlp2(s.obsh, s.u.bk.W.av.av1H, s.u.bk.W.av.av2H, s.u.bk.av1b, s.u.bk.av2b, s.u.bk.APT, az, lane, acc2);
#pragma unroll
    for (int nt = 0; nt < 4; nt++)
#pragma unroll
      for (int reg = 0; reg < 4; reg++)
        s.u.bk.APT[(nt * 16 + m) * 24 + quad * 4 + reg] = (f16)acc2[nt][reg];
  }
  if (w == 1) {
    v8h az = {};
    if (quad == 0) {
      const float wv = s.wsig[m * 16 + m];
#pragma unroll
      for (int c = 0; c < 8; c++)
        az[c] = (f16)(s.pi[m * 8 + c] + wv * (s.act[m * 8 + c] - s.pi[m * 8 + c]));
    }
    v4f acc2[4];
    av_mlp2(s.obsh, s.u.bk.W.av.av1H, s.u.bk.W.av.av2H, s.u.bk.av1b, s.u.bk.av2b, s.u.bk.AOsrcD, az, lane, acc2);
#pragma unroll
    for (int nt = 0; nt < 4; nt++)
#pragma unroll
      for (int reg = 0; reg < 4; reg++)
        s.u.bk.AOsrcD[(quad * 4 + reg) * 72 + nt * 16 + m] = (f16)acc2[nt][reg];
  }
  __syncthreads();

  // ---- P12: fv1H from registers ----
#pragma unroll
  for (int qq = 0; qq < 4; qq++) {
    const int e0 = tid * 16 + qq * 4;
    h2* d = (h2*)&s.u.bk.W.fv1H[(e0 >> 7) * 136 + (e0 & 127)];
    d[0] = h2{(f16)rfv[qq].x, (f16)rfv[qq].y};
    d[1] = h2{(f16)rfv[qq].z, (f16)rfv[qq].w};
  }
  __syncthreads();

  // ---- P13: mixed + fv1 + fv2 + out0 ----
  {
    const v8h am = *(const v8h*)(&s.u.bk.AextH[m * 40 + quad * 8]);
    v4f macc[4];
#pragma unroll
    for (int nt = 0; nt < 4; nt++) {
      const int oo = nt * 16 + m;
      v8h bf;
      if (quad < 2) {
        bf = *(const v8h*)(Sl + oo * 24 + quad * 8);
      } else {
        const v8h apv = *(const v8h*)(&s.u.bk.APT[oo * 24 + (quad - 2) * 8]);
        const v8h aov = *(const v8h*)(Sl + oo * 24 + (quad - 2) * 8);
        bf = apv - aov;
      }
      v4f z4 = {0.f, 0.f, 0.f, 0.f};
      macc[nt] = __builtin_amdgcn_mfma_f32_16x16x32_f16(am, bf, z4, 0, 0, 0);
    }
#pragma unroll
    for (int nt = 0; nt < 4; nt++)
#pragma unroll
      for (int reg = 0; reg < 4; reg++)
        Sl[(quad * 4 + reg) * 72 + nt * 16 + m] = (f16)macc[nt][reg];
  }
  {
    const v8h f0 = *(const v8h*)(&s.u.bk.AOsrcD[m * 72 + quad * 8]);
    const v8h f1 = *(const v8h*)(&s.u.bk.AOsrcD[m * 72 + 32 + quad * 8]);
    const v8h f2 = *(const v8h*)(Sl + m * 72 + quad * 8);
    const v8h f3 = *(const v8h*)(Sl + m * 72 + 32 + quad * 8);
#pragma unroll
    for (int nt = 0; nt < 4; nt++) {
      const float bv = s.u.bk.fv1b[nt * 16 + m];
      v4f acc = {bv, bv, bv, bv};
      acc = __builtin_amdgcn_mfma_f32_16x16x32_f16(f0, bfrag(s.u.bk.W.fv1H, 136, nt, 0, lane), acc, 0, 0, 0);
      acc = __builtin_amdgcn_mfma_f32_16x16x32_f16(f1, bfrag(s.u.bk.W.fv1H, 136, nt, 1, lane), acc, 0, 0, 0);
      acc = __builtin_amdgcn_mfma_f32_16x16x32_f16(f2, bfrag(s.u.bk.W.fv1H, 136, nt, 2, lane), acc, 0, 0, 0);
      acc = __builtin_amdgcn_mfma_f32_16x16x32_f16(f3, bfrag(s.u.bk.W.fv1H, 136, nt, 3, lane), acc, 0, 0, 0);
#pragma unroll
      for (int reg = 0; reg < 4; reg++)
        Sl[(quad * 4 + reg) * 72 + nt * 16 + m] = (f16)lrelu(acc[reg]);
    }
  }
  {
    const int g2 = quad;
    float y0 = s.u.bk.fv2b[2 * g2], y1 = s.u.bk.fv2b[2 * g2 + 1];
#pragma unroll
    for (int o2 = 0; o2 < 32; o2++) {
      const h2 hh = *(const h2*)(Sl + m * 72 + 2 * o2);
      const h2 w0 = *(const h2*)(&s.u.bk.fv2pw[(2 * g2) * 64 + 2 * o2]);
      const h2 w1 = *(const h2*)(&s.u.bk.fv2pw[(2 * g2 + 1) * 64 + 2 * o2]);
      y0 = fdot2f(w0, hh, y0);
      y1 = fdot2f(w1, hh, y1);
    }
    *(float2*)(p.out0 + ((size_t)b * 256 + i_ * 16 + m) * 8 + 2 * g2) = make_float2(y0, y1);
  }
}

extern "C" void kernel_launch(void* const* d_in, const int* in_sizes, int n_in,
                              void* d_out, int out_size, void* d_ws, size_t ws_size,
                              hipStream_t stream) {
  P p;
  p.obs = (const float*)d_in[0];
  p.pol = (const float*)d_in[1];
  p.act = (const float*)d_in[2];
  p.kw1w = (const float*)d_in[3];  p.kw1b = (const float*)d_in[4];
  p.kw2w = (const float*)d_in[5];  p.kw2b = (const float*)d_in[6];
  p.qw1w = (const float*)d_in[7];  p.qw1b = (const float*)d_in[8];
  p.qw2w = (const float*)d_in[9];  p.qw2b = (const float*)d_in[10];
  p.ko1w = (const float*)d_in[11]; p.ko1b = (const float*)d_in[12];
  p.ko2w = (const float*)d_in[13]; p.ko2b = (const float*)d_in[14];
  p.qo1w = (const float*)d_in[15]; p.qo1b = (const float*)d_in[16];
  p.qo2w = (const float*)d_in[17]; p.qo2b = (const float*)d_in[18];
  p.av1w = (const float*)d_in[19]; p.av1b = (const float*)d_in[20];
  p.av2w = (const float*)d_in[21]; p.av2b = (const float*)d_in[22];
  p.fv1w = (const float*)d_in[23]; p.fv1b = (const float*)d_in[24];
  p.fv2w = (const float*)d_in[25]; p.fv2b = (const float*)d_in[26];

  const int Bn = in_sizes[0] / (A_ * DOBS_);   // 128
  p.out0 = (float*)d_out;
  p.out1 = p.out0 + (size_t)Bn * A_ * A_ * NA_;
  p.out2 = p.out1 + (size_t)Bn * A_ * A_;

  hipLaunchKernelGGL(critic_fused, dim3(2 * Bn), dim3(512), 0, stream, p);
}